// Round 3
// baseline (691.164 us; speedup 1.0000x reference)
//
#include <hip/hip_runtime.h>
#include <math.h>

// Model8 R3: (1) XL packed as bf16 into 32B-aligned rows -> 1 cache line per
// edge gather (was ~1.75) and 3.2MB L2-resident; (2) k_hist 4 edges/thread
// (atomic MLP) and self-loops done without atomics (deg init=1, slot 0);
// (3) software-pipelined gather with sidx prefetch.

#define PAD 12  // padded row stride for fp32 [N,10] arrays
#define LP 8    // XLb packed row stride in u32 (32B, line-aligned)

__device__ __forceinline__ float lrelu02(float v) { return v > 0.f ? v : 0.2f * v; }

// round-to-nearest-even bf16 pack of two floats into one u32 (lo,hi)
__device__ __forceinline__ unsigned pk_bf16(float a, float b)
{
    unsigned ua = __float_as_uint(a), ub = __float_as_uint(b);
    ua += 0x7fffu + ((ua >> 16) & 1u);
    ub += 0x7fffu + ((ub >> 16) & 1u);
    return (ua >> 16) | (ub & 0xffff0000u);
}
__device__ __forceinline__ float bf_lo(unsigned u) { return __uint_as_float(u << 16); }
__device__ __forceinline__ float bf_hi(unsigned u) { return __uint_as_float(u & 0xffff0000u); }

// x_ = relu(x1 @ init_W + init_b); deg[n]=1 (self-loop owns slot 0); zero vsums.
__global__ void k_init(const float* __restrict__ x1, const float* __restrict__ W,
                       const float* __restrict__ b, float* __restrict__ xo,
                       int* __restrict__ deg, float* __restrict__ vsums, int N)
{
    __shared__ float sW[150];
    __shared__ float sb[10];
    int t = threadIdx.x;
    if (t < 150) sW[t] = W[t];
    if (t < 10) sb[t] = b[t];
    if (blockIdx.x == 0 && t < 16) vsums[t] = 0.f;
    __syncthreads();
    int n = blockIdx.x * blockDim.x + t;
    if (n >= N) return;
    deg[n] = 1;
    float f[15];
#pragma unroll
    for (int k = 0; k < 15; ++k) f[k] = x1[n * 15 + k];
#pragma unroll
    for (int g = 0; g < 10; ++g) {
        float s = sb[g];
#pragma unroll
        for (int k = 0; k < 15; ++k) s += f[k] * sW[k * 10 + g];
        xo[n * PAD + g] = fmaxf(s, 0.f);
    }
    xo[n * PAD + 10] = 0.f;
    xo[n * PAD + 11] = 0.f;
}

// CSR pass 1: degree histogram over real edges only; 4 edges/thread for MLP.
__global__ void k_hist(const int* __restrict__ edst, int E,
                       int* __restrict__ deg, int* __restrict__ pos)
{
    int base = (blockIdx.x * blockDim.x + threadIdx.x) * 4;
    if (base + 3 < E) {
        int4 d4 = *(const int4*)(edst + base);
        int p0 = atomicAdd(&deg[d4.x], 1);
        int p1 = atomicAdd(&deg[d4.y], 1);
        int p2 = atomicAdd(&deg[d4.z], 1);
        int p3 = atomicAdd(&deg[d4.w], 1);
        pos[base + 0] = p0;
        pos[base + 1] = p1;
        pos[base + 2] = p2;
        pos[base + 3] = p3;
    } else {
        for (int k = 0; k < 4; ++k) {
            int i = base + k;
            if (i < E) pos[i] = atomicAdd(&deg[edst[i]], 1);
        }
    }
}

// Exclusive scan of deg -> rowptr. Two-level: per-block scan + block sums.
__global__ __launch_bounds__(1024) void k_scan1(const int* __restrict__ deg,
                                                int* __restrict__ rowptr,
                                                int* __restrict__ bsum, int N)
{
    __shared__ int wsum[16];
    int t = threadIdx.x;
    int i = blockIdx.x * 1024 + t;
    int lane = t & 63, w = t >> 6;
    int x = (i < N) ? deg[i] : 0;
    int incl = x;
#pragma unroll
    for (int off = 1; off < 64; off <<= 1) {
        int u = __shfl_up(incl, off);
        if (lane >= off) incl += u;
    }
    if (lane == 63) wsum[w] = incl;
    __syncthreads();
    int woff = 0;
    for (int k = 0; k < w; ++k) woff += wsum[k];
    incl += woff;
    if (i < N) rowptr[i] = incl - x;
    if (t == 1023) bsum[blockIdx.x] = incl;
}

__global__ void k_scan2(const int* __restrict__ bsum, int* __restrict__ boff,
                        int* __restrict__ rowptr, int NBLK, int N)
{
    if (threadIdx.x == 0 && blockIdx.x == 0) {
        int run = 0;
        for (int b = 0; b < NBLK; ++b) { boff[b] = run; run += bsum[b]; }
        rowptr[N] = run;
    }
}

__global__ __launch_bounds__(1024) void k_scan3(int* __restrict__ rowptr,
                                                const int* __restrict__ boff, int N)
{
    int i = blockIdx.x * 1024 + threadIdx.x;
    if (i < N) rowptr[i] += boff[blockIdx.x];
}

// CSR pass 2: scatter. Real edges use pos (>=1); self-loops take slot 0.
__global__ void k_scatter(const int* __restrict__ esrc, const int* __restrict__ edst,
                          int E, int Etot, const int* __restrict__ rowptr,
                          const int* __restrict__ pos, int* __restrict__ sidx)
{
    int i = blockIdx.x * blockDim.x + threadIdx.x;
    if (i >= Etot) return;
    if (i < E) {
        int s = esrc[i], d = edst[i];
        sidx[rowptr[d] + pos[i]] = s;
    } else {
        int n = i - E;
        sidx[rowptr[n]] = n;
    }
}

// Per-node: xl = f @ Wl (packed bf16), xr = f @ Wr (fp32), f = concat(s0..,x1).
template <int NS>
__global__ void k_transform(const float* __restrict__ s0, const float* __restrict__ s1,
                            const float* __restrict__ s2, const float* __restrict__ x1,
                            const float* __restrict__ Wl, const float* __restrict__ Wr,
                            unsigned* __restrict__ XLb, float* __restrict__ XR, int N)
{
    constexpr int FIN = NS * 10 + 15;
    __shared__ float sWl[FIN * 10];
    __shared__ float sWr[FIN * 10];
    for (int i = threadIdx.x; i < FIN * 10; i += blockDim.x) {
        sWl[i] = Wl[i];
        sWr[i] = Wr[i];
    }
    __syncthreads();
    int n = blockIdx.x * blockDim.x + threadIdx.x;
    if (n >= N) return;
    float f[FIN];
    int o = 0;
    if constexpr (NS >= 1) {
#pragma unroll
        for (int g = 0; g < 10; ++g) f[o++] = s0[n * PAD + g];
    }
    if constexpr (NS >= 2) {
#pragma unroll
        for (int g = 0; g < 10; ++g) f[o++] = s1[n * PAD + g];
    }
    if constexpr (NS >= 3) {
#pragma unroll
        for (int g = 0; g < 10; ++g) f[o++] = s2[n * PAD + g];
    }
#pragma unroll
    for (int k = 0; k < 15; ++k) f[o++] = x1[n * 15 + k];
    float al[10], ar[10];
#pragma unroll
    for (int g = 0; g < 10; ++g) {
        float a = 0.f, r = 0.f;
#pragma unroll
        for (int k = 0; k < FIN; ++k) {
            a += f[k] * sWl[k * 10 + g];
            r += f[k] * sWr[k * 10 + g];
        }
        al[g] = a;
        ar[g] = r;
    }
    uint4 q0;
    q0.x = pk_bf16(al[0], al[1]);
    q0.y = pk_bf16(al[2], al[3]);
    q0.z = pk_bf16(al[4], al[5]);
    q0.w = pk_bf16(al[6], al[7]);
    uint4 q1;
    q1.x = pk_bf16(al[8], al[9]);
    q1.y = 0; q1.z = 0; q1.w = 0;
    uint4* pb = (uint4*)(XLb + (size_t)n * LP);
    pb[0] = q0;
    pb[1] = q1;
#pragma unroll
    for (int g = 0; g < 10; ++g) XR[n * PAD + g] = ar[g];
    XR[n * PAD + 10] = 0.f;
    XR[n * PAD + 11] = 0.f;
}

// CSR gather + edge softmax + finalize. 8 lanes per dst node; bf16 XL rows
// (1 cache line/edge); sidx software prefetch.
__global__ __launch_bounds__(256) void k_gather(
    const int* __restrict__ rowptr, const int* __restrict__ deg,
    const int* __restrict__ sidx,
    const unsigned* __restrict__ XLb, const float* __restrict__ XR,
    const float* __restrict__ att, const float* __restrict__ b,
    float* __restrict__ xo, int N)
{
    __shared__ float satt[10], sb[10];
    if (threadIdx.x < 10) { satt[threadIdx.x] = att[threadIdx.x]; sb[threadIdx.x] = b[threadIdx.x]; }
    __syncthreads();
    int node = blockIdx.x * 32 + (threadIdx.x >> 3);
    int l8 = threadIdx.x & 7;
    float acc[10];
#pragma unroll
    for (int g = 0; g < 10; ++g) acc[g] = 0.f;
    float den = 0.f;
    if (node < N) {
        const float4* pr = (const float4*)(XR + node * PAD);
        float4 r0 = pr[0], r1 = pr[1], r2 = pr[2];
        float xr[10] = {r0.x, r0.y, r0.z, r0.w, r1.x, r1.y, r1.z, r1.w, r2.x, r2.y};
        int start = rowptr[node];
        int dgr = deg[node];
        int j = l8;
        int sn = (j < dgr) ? sidx[start + j] : 0;
        while (j < dgr) {
            int s = sn;
            int jn = j + 8;
            sn = (jn < dgr) ? sidx[start + jn] : 0;
            const unsigned* pl = XLb + (size_t)s * LP;
            uint4 q = *(const uint4*)pl;
            unsigned q4 = pl[4];
            float xl[10] = {bf_lo(q.x), bf_hi(q.x), bf_lo(q.y), bf_hi(q.y),
                            bf_lo(q.z), bf_hi(q.z), bf_lo(q.w), bf_hi(q.w),
                            bf_lo(q4), bf_hi(q4)};
            float e = 0.f;
#pragma unroll
            for (int g = 0; g < 10; ++g) e += lrelu02(xl[g] + xr[g]) * satt[g];
            float ex = __expf(e);
#pragma unroll
            for (int g = 0; g < 10; ++g) acc[g] += ex * xl[g];
            den += ex;
            j = jn;
        }
    }
#pragma unroll
    for (int off = 1; off < 8; off <<= 1) {
        den += __shfl_xor(den, off);
#pragma unroll
        for (int g = 0; g < 10; ++g) acc[g] += __shfl_xor(acc[g], off);
    }
    if (node < N && l8 == 0) {
        float inv = 1.f / den;
#pragma unroll
        for (int g = 0; g < 10; ++g)
            xo[node * PAD + g] = fmaxf(acc[g] * inv + sb[g], 0.f);
        xo[node * PAD + 10] = 0.f;
        xo[node * PAD + 11] = 0.f;
    }
}

// Value head accumulation: per node w = exp(v@va+vab), wv = w*(v@vv+vvb).
__global__ void k_value(const float* __restrict__ xc, const float* __restrict__ x1,
                        const float* __restrict__ x2,
                        const float* __restrict__ vtW, const float* __restrict__ vtb,
                        const float* __restrict__ vaW, const float* __restrict__ vab,
                        const float* __restrict__ vvW, const float* __restrict__ vvb,
                        float* __restrict__ vsums, int N)
{
    __shared__ float sW[580];   // 29x20
    __shared__ float svv[200];  // 20x10
    __shared__ float sb20[20], sva[20], svvb[10], sx2[4];
    __shared__ float svab;
    __shared__ float sred[4][11];
    int t = threadIdx.x;
    for (int i = t; i < 580; i += blockDim.x) sW[i] = vtW[i];
    for (int i = t; i < 200; i += blockDim.x) svv[i] = vvW[i];
    if (t < 20) sb20[t] = vtb[t];
    if (t >= 32 && t < 52) sva[t - 32] = vaW[t - 32];
    if (t >= 64 && t < 74) svvb[t - 64] = vvb[t - 64];
    if (t >= 96 && t < 100) sx2[t - 96] = x2[t - 96];
    if (t == 128) svab = vab[0];
    __syncthreads();
    int n = blockIdx.x * blockDim.x + t;
    float w = 0.f;
    float wv[10];
#pragma unroll
    for (int c = 0; c < 10; ++c) wv[c] = 0.f;
    if (n < N) {
        float f[29];
#pragma unroll
        for (int k = 0; k < 10; ++k) f[k] = xc[n * PAD + k];
#pragma unroll
        for (int k = 0; k < 15; ++k) f[10 + k] = x1[n * 15 + k];
#pragma unroll
        for (int k = 0; k < 4; ++k) f[25 + k] = sx2[k];
        float v[20];
#pragma unroll
        for (int j = 0; j < 20; ++j) {
            float s = sb20[j];
#pragma unroll
            for (int k = 0; k < 29; ++k) s += f[k] * sW[k * 20 + j];
            v[j] = fmaxf(s, 0.f);
        }
        float sc = svab;
#pragma unroll
        for (int j = 0; j < 20; ++j) sc += v[j] * sva[j];
        w = __expf(sc);
#pragma unroll
        for (int c = 0; c < 10; ++c) {
            float t2 = svvb[c];
#pragma unroll
            for (int j = 0; j < 20; ++j) t2 += v[j] * svv[j * 10 + c];
            wv[c] = w * t2;
        }
    }
#pragma unroll
    for (int off = 32; off > 0; off >>= 1) {
        w += __shfl_xor(w, off);
#pragma unroll
        for (int c = 0; c < 10; ++c) wv[c] += __shfl_xor(wv[c], off);
    }
    int wave = t >> 6, lane = t & 63;
    if (lane == 0) {
        sred[wave][0] = w;
#pragma unroll
        for (int c = 0; c < 10; ++c) sred[wave][1 + c] = wv[c];
    }
    __syncthreads();
    if (t == 0) {
#pragma unroll
        for (int c = 0; c < 11; ++c) {
            float s = sred[0][c] + sred[1][c] + sred[2][c] + sred[3][c];
            atomicAdd(&vsums[c], s);
        }
    }
}

// V = tanh(relu(wv/w) @ vl_W + vl_b)
__global__ void k_value2(const float* __restrict__ vsums, const float* __restrict__ vlW,
                         const float* __restrict__ vlb, float* __restrict__ out)
{
    if (threadIdx.x == 0 && blockIdx.x == 0) {
        float inv = 1.f / vsums[0];
        float V = vlb[0];
#pragma unroll
        for (int j = 0; j < 10; ++j) V += fmaxf(vsums[1 + j] * inv, 0.f) * vlW[j];
        out[0] = tanhf(V);
    }
}

// Policy: one wave per move; lane<32 -> attack order, lane in [32,48) -> deploy order.
__global__ __launch_bounds__(256) void k_policy(
    const int* __restrict__ asrc, const int* __restrict__ adst,
    const float* __restrict__ aarm,
    const int* __restrict__ dtgt, const float* __restrict__ darm,
    const float* __restrict__ xc, const float* __restrict__ x1,
    const float* __restrict__ atW, const float* __restrict__ atb,
    const float* __restrict__ dtW, const float* __restrict__ dtb,
    const float* __restrict__ oaW, const float* __restrict__ oab,
    const float* __restrict__ ovW, const float* __restrict__ ovb,
    float* __restrict__ pm, int M)
{
    __shared__ float sat[960];  // 48x20
    __shared__ float sdt[460];  // 23x20
    __shared__ float satb[20], sdtb[20], soa[20], sov[20];
    __shared__ float soab, sovb;
    for (int i = threadIdx.x; i < 960; i += 256) sat[i] = atW[i];
    for (int i = threadIdx.x; i < 460; i += 256) sdt[i] = dtW[i];
    if (threadIdx.x < 20) {
        satb[threadIdx.x] = atb[threadIdx.x];
        sdtb[threadIdx.x] = dtb[threadIdx.x];
        soa[threadIdx.x] = oaW[threadIdx.x];
        sov[threadIdx.x] = ovW[threadIdx.x];
    }
    if (threadIdx.x == 32) { soab = oab[0]; sovb = ovb[0]; }
    __syncthreads();
    int wave = threadIdx.x >> 6, lane = threadIdx.x & 63;
    int m = blockIdx.x * 4 + wave;
    float asc = -1e30f, vsc = 0.f;
    if (m < M) {
        float ord[20];
        bool have = false;
        if (lane < 32) {
            int a = lane;
            int s = asrc[m * 32 + a], d = adst[m * 32 + a];
            float arm = aarm[m * 32 + a];
            float feat[48];
#pragma unroll
            for (int g = 0; g < 10; ++g) feat[g] = xc[s * PAD + g];
#pragma unroll
            for (int g = 0; g < 10; ++g) feat[10 + g] = xc[d * PAD + g];
#pragma unroll
            for (int k = 0; k < 12; ++k) feat[20 + k] = x1[s * 15 + 3 + k];
            float x1d[15];
#pragma unroll
            for (int k = 0; k < 15; ++k) x1d[k] = x1[d * 15 + k];
#pragma unroll
            for (int k = 0; k < 14; ++k) feat[32 + k] = x1d[1 + k];
            feat[46] = arm;
            feat[47] = 0.6f * arm - 0.7f * (x1d[3] + x1d[4]);
#pragma unroll
            for (int j = 0; j < 20; ++j) {
                float s2 = satb[j];
#pragma unroll
                for (int k = 0; k < 48; ++k) s2 += feat[k] * sat[k * 20 + j];
                ord[j] = fmaxf(s2, 0.f);
            }
            have = true;
        } else if (lane < 48) {
            int dd = lane - 32;
            int tg = dtgt[m * 16 + dd];
            float arm = darm[m * 16 + dd];
            float feat[23];
#pragma unroll
            for (int g = 0; g < 10; ++g) feat[g] = xc[tg * PAD + g];
#pragma unroll
            for (int k = 0; k < 12; ++k) feat[10 + k] = x1[tg * 15 + 3 + k];
            feat[22] = arm;
#pragma unroll
            for (int j = 0; j < 20; ++j) {
                float s2 = sdtb[j];
#pragma unroll
                for (int k = 0; k < 23; ++k) s2 += feat[k] * sdt[k * 20 + j];
                ord[j] = fmaxf(s2, 0.f);
            }
            have = true;
        }
        if (have) {
            asc = soab; vsc = sovb;
#pragma unroll
            for (int j = 0; j < 20; ++j) {
                asc += ord[j] * soa[j];
                vsc += ord[j] * sov[j];
            }
        }
    }
    float mx = asc;
#pragma unroll
    for (int off = 32; off > 0; off >>= 1) mx = fmaxf(mx, __shfl_xor(mx, off));
    float p = (asc > -1e29f) ? __expf(asc - mx) : 0.f;
    float num = p * vsc;
    float Z = p;
#pragma unroll
    for (int off = 32; off > 0; off >>= 1) {
        Z += __shfl_xor(Z, off);
        num += __shfl_xor(num, off);
    }
    if (m < M && lane == 0) pm[m] = num / Z;
}

// out[1..M] = log_softmax(pm)
__global__ void k_logsoftmax(const float* __restrict__ pm, float* __restrict__ out, int M)
{
    __shared__ float red[16];
    __shared__ float sval;
    int t = threadIdx.x;
    int wave = t >> 6, lane = t & 63;
    float mx = -1e30f;
    for (int i = t; i < M; i += 1024) mx = fmaxf(mx, pm[i]);
#pragma unroll
    for (int off = 32; off > 0; off >>= 1) mx = fmaxf(mx, __shfl_xor(mx, off));
    if (lane == 0) red[wave] = mx;
    __syncthreads();
    if (t == 0) {
        float m2 = red[0];
        for (int i = 1; i < 16; ++i) m2 = fmaxf(m2, red[i]);
        sval = m2;
    }
    __syncthreads();
    float smax = sval;
    float sum = 0.f;
    for (int i = t; i < M; i += 1024) sum += __expf(pm[i] - smax);
#pragma unroll
    for (int off = 32; off > 0; off >>= 1) sum += __shfl_xor(sum, off);
    if (lane == 0) red[wave] = sum;
    __syncthreads();
    if (t == 0) {
        float s2 = 0.f;
        for (int i = 0; i < 16; ++i) s2 += red[i];
        sval = s2;
    }
    __syncthreads();
    float lse = smax + logf(sval);
    for (int i = t; i < M; i += 1024) out[1 + i] = pm[i] - lse;
}

extern "C" void kernel_launch(void* const* d_in, const int* in_sizes, int n_in,
                              void* d_out, int out_size, void* d_ws, size_t ws_size,
                              hipStream_t stream)
{
    const float* x1   = (const float*)d_in[0];
    const float* x2   = (const float*)d_in[1];
    const int*   edges = (const int*)d_in[2];
    const int*   asrc = (const int*)d_in[3];
    const int*   adst = (const int*)d_in[4];
    const float* aarm = (const float*)d_in[5];
    const int*   dtgt = (const int*)d_in[6];
    const float* darm = (const float*)d_in[7];
    const float* initW = (const float*)d_in[8];
    const float* initb = (const float*)d_in[9];
    const float* g1Wl = (const float*)d_in[10];
    const float* g1Wr = (const float*)d_in[11];
    const float* g1att = (const float*)d_in[12];
    const float* g1b = (const float*)d_in[13];
    const float* g2Wl = (const float*)d_in[14];
    const float* g2Wr = (const float*)d_in[15];
    const float* g2att = (const float*)d_in[16];
    const float* g2b = (const float*)d_in[17];
    const float* g3Wl = (const float*)d_in[18];
    const float* g3Wr = (const float*)d_in[19];
    const float* g3att = (const float*)d_in[20];
    const float* g3b = (const float*)d_in[21];
    const float* vtW = (const float*)d_in[22];
    const float* vtb = (const float*)d_in[23];
    const float* vaW = (const float*)d_in[24];
    const float* vab = (const float*)d_in[25];
    const float* vvW = (const float*)d_in[26];
    const float* vvb = (const float*)d_in[27];
    const float* vlW = (const float*)d_in[28];
    const float* vlb = (const float*)d_in[29];
    const float* atW = (const float*)d_in[30];
    const float* atb = (const float*)d_in[31];
    const float* dtW = (const float*)d_in[32];
    const float* dtb = (const float*)d_in[33];
    const float* oaW = (const float*)d_in[34];
    const float* oab = (const float*)d_in[35];
    const float* ovW = (const float*)d_in[36];
    const float* ovb = (const float*)d_in[37];

    const int N = in_sizes[0] / 15;
    const int E = in_sizes[2] / 2;
    const int M = in_sizes[3] / 32;
    const int Etot = E + N;

    float* ws = (float*)d_ws;
    size_t off = 0;
    float* XU = ws + off; off += (size_t)N * PAD;  // x_
    float* XA = ws + off; off += (size_t)N * PAD;
    float* XB = ws + off; off += (size_t)N * PAD;
    float* XC = ws + off; off += (size_t)N * PAD;
    unsigned* XLb = (unsigned*)(ws + off); off += (size_t)N * LP;
    float* XR = ws + off; off += (size_t)N * PAD;
    int* sidx = (int*)(ws + off); off += Etot;
    int* deg = (int*)(ws + off); off += N;
    int* rowptr = (int*)(ws + off); off += N + 8;
    int* bsum = (int*)(ws + off); off += 128;
    int* boff = (int*)(ws + off); off += 128;
    float* VS = ws + off; off += 16;
    float* PM = ws + off; off += M;
    // pos overlays XA..XC (3*N*PAD >= E); dead before first k_gather.
    int* pos = (int*)XA;

    float* outp = (float*)d_out;

    const int NB = (N + 255) / 256;
    const int EB = (Etot + 255) / 256;
    const int HB = (E + 1023) / 1024;   // hist: 4 edges/thread
    const int NG = (N + 31) / 32;       // gather: 8 lanes/node, 32 nodes/block
    const int NSC = (N + 1023) / 1024;  // scan blocks
    const int* esrc = edges;
    const int* edst = edges + E;

    k_init<<<NB, 256, 0, stream>>>(x1, initW, initb, XU, deg, VS, N);

    // CSR build (shared by all 3 layers)
    k_hist<<<HB, 256, 0, stream>>>(edst, E, deg, pos);
    k_scan1<<<NSC, 1024, 0, stream>>>(deg, rowptr, bsum, N);
    k_scan2<<<1, 64, 0, stream>>>(bsum, boff, rowptr, NSC, N);
    k_scan3<<<NSC, 1024, 0, stream>>>(rowptr, boff, N);
    k_scatter<<<EB, 256, 0, stream>>>(esrc, edst, E, Etot, rowptr, pos, sidx);

    // Layer 1: f = [x_, x1]
    k_transform<1><<<NB, 256, 0, stream>>>(XU, nullptr, nullptr, x1, g1Wl, g1Wr, XLb, XR, N);
    k_gather<<<NG, 256, 0, stream>>>(rowptr, deg, sidx, XLb, XR, g1att, g1b, XA, N);

    // Layer 2: f = [xa, x_, x1]
    k_transform<2><<<NB, 256, 0, stream>>>(XA, XU, nullptr, x1, g2Wl, g2Wr, XLb, XR, N);
    k_gather<<<NG, 256, 0, stream>>>(rowptr, deg, sidx, XLb, XR, g2att, g2b, XB, N);

    // Layer 3: f = [xb, xa, x_, x1]
    k_transform<3><<<NB, 256, 0, stream>>>(XB, XA, XU, x1, g3Wl, g3Wr, XLb, XR, N);
    k_gather<<<NG, 256, 0, stream>>>(rowptr, deg, sidx, XLb, XR, g3att, g3b, XC, N);

    // Value head
    k_value<<<NB, 256, 0, stream>>>(XC, x1, x2, vtW, vtb, vaW, vab, vvW, vvb, VS, N);
    k_value2<<<1, 64, 0, stream>>>(VS, vlW, vlb, outp);

    // Policy head
    k_policy<<<(M + 3) / 4, 256, 0, stream>>>(asrc, adst, aarm, dtgt, darm, XC, x1,
                                              atW, atb, dtW, dtb, oaW, oab, ovW, ovb, PM, M);
    k_logsoftmax<<<1, 1024, 0, stream>>>(PM, outp, M);
}

// Round 4
// 664.589 us; speedup vs baseline: 1.0400x; 1.0400x over previous
//
#include <hip/hip_runtime.h>
#include <math.h>

// Model8 R4: revert hist to 1-edge/thread (4/thread measured -10%); fuse
// independent dispatches (init||hist, scatter||transform1, value||policy,
// value2+logsoftmax, self-loops into scan3); gather = 16 lanes/node plain
// loop (no manual prefetch), bf16-packed XL rows (1 line/edge, L2-resident).

#define PAD 12  // padded row stride for fp32 [N,10] arrays
#define LP 8    // XLb packed row stride in u32 (32B, line-aligned)

__device__ __forceinline__ float lrelu02(float v) { return v > 0.f ? v : 0.2f * v; }

// round-to-nearest-even bf16 pack of two floats into one u32 (lo,hi)
__device__ __forceinline__ unsigned pk_bf16(float a, float b)
{
    unsigned ua = __float_as_uint(a), ub = __float_as_uint(b);
    ua += 0x7fffu + ((ua >> 16) & 1u);
    ub += 0x7fffu + ((ub >> 16) & 1u);
    return (ua >> 16) | (ub & 0xffff0000u);
}
__device__ __forceinline__ float bf_lo(unsigned u) { return __uint_as_float(u << 16); }
__device__ __forceinline__ float bf_hi(unsigned u) { return __uint_as_float(u & 0xffff0000u); }

// deg[n]=1 (self-loop owns slot 0); zero value-head sums. Must precede hist.
__global__ void k_degset(int* __restrict__ deg, float* __restrict__ vsums, int N)
{
    int i = blockIdx.x * blockDim.x + threadIdx.x;
    if (i < N) deg[i] = 1;
    if (blockIdx.x == 0 && threadIdx.x < 16) vsums[threadIdx.x] = 0.f;
}

// Fused: blocks [0,NB) -> x_ = relu(x1@init_W+init_b); [NB,..) -> degree hist
// (1 edge/thread, returning atomic gives within-row slot, slots start at 1).
__global__ __launch_bounds__(256) void k_init_hist(
    const float* __restrict__ x1, const float* __restrict__ W,
    const float* __restrict__ b, float* __restrict__ xo,
    const int* __restrict__ edst, int E,
    int* __restrict__ deg, int* __restrict__ pos, int NB, int N)
{
    if ((int)blockIdx.x < NB) {
        __shared__ float sW[150];
        __shared__ float sb[10];
        int t = threadIdx.x;
        if (t < 150) sW[t] = W[t];
        if (t < 10) sb[t] = b[t];
        __syncthreads();
        int n = blockIdx.x * blockDim.x + t;
        if (n >= N) return;
        float f[15];
#pragma unroll
        for (int k = 0; k < 15; ++k) f[k] = x1[n * 15 + k];
#pragma unroll
        for (int g = 0; g < 10; ++g) {
            float s = sb[g];
#pragma unroll
            for (int k = 0; k < 15; ++k) s += f[k] * sW[k * 10 + g];
            xo[n * PAD + g] = fmaxf(s, 0.f);
        }
        xo[n * PAD + 10] = 0.f;
        xo[n * PAD + 11] = 0.f;
    } else {
        int i = ((int)blockIdx.x - NB) * 256 + (int)threadIdx.x;
        if (i < E) pos[i] = atomicAdd(&deg[edst[i]], 1);
    }
}

// Exclusive scan of deg -> rowptr. Two-level: per-block scan + block sums.
__global__ __launch_bounds__(1024) void k_scan1(const int* __restrict__ deg,
                                                int* __restrict__ rowptr,
                                                int* __restrict__ bsum, int N)
{
    __shared__ int wsum[16];
    int t = threadIdx.x;
    int i = blockIdx.x * 1024 + t;
    int lane = t & 63, w = t >> 6;
    int x = (i < N) ? deg[i] : 0;
    int incl = x;
#pragma unroll
    for (int off = 1; off < 64; off <<= 1) {
        int u = __shfl_up(incl, off);
        if (lane >= off) incl += u;
    }
    if (lane == 63) wsum[w] = incl;
    __syncthreads();
    int woff = 0;
    for (int k = 0; k < w; ++k) woff += wsum[k];
    incl += woff;
    if (i < N) rowptr[i] = incl - x;
    if (t == 1023) bsum[blockIdx.x] = incl;
}

__global__ void k_scan2(const int* __restrict__ bsum, int* __restrict__ boff,
                        int* __restrict__ rowptr, int NBLK, int N)
{
    if (threadIdx.x == 0 && blockIdx.x == 0) {
        int run = 0;
        for (int b = 0; b < NBLK; ++b) { boff[b] = run; run += bsum[b]; }
        rowptr[N] = run;
    }
}

// Finalize rowptr AND place self-loops (slot 0 of each row).
__global__ __launch_bounds__(1024) void k_scan3(int* __restrict__ rowptr,
                                                const int* __restrict__ boff,
                                                int* __restrict__ sidx, int N)
{
    int i = blockIdx.x * 1024 + threadIdx.x;
    if (i < N) {
        int r = rowptr[i] + boff[blockIdx.x];
        rowptr[i] = r;
        sidx[r] = i;
    }
}

// Fused: blocks [0,NB) -> transform layer1 (xl=f@Wl packed bf16, xr=f@Wr);
// [NB,..) -> scatter real edges into CSR slots (>=1).
__global__ __launch_bounds__(256) void k_scat_tr1(
    const int* __restrict__ esrc, const int* __restrict__ edst, int E,
    const int* __restrict__ rowptr, const int* __restrict__ pos,
    int* __restrict__ sidx,
    const float* __restrict__ s0, const float* __restrict__ x1,
    const float* __restrict__ Wl, const float* __restrict__ Wr,
    unsigned* __restrict__ XLb, float* __restrict__ XR, int NB, int N)
{
    if ((int)blockIdx.x < NB) {
        constexpr int FIN = 25;
        __shared__ float sWl[FIN * 10];
        __shared__ float sWr[FIN * 10];
        for (int i = threadIdx.x; i < FIN * 10; i += blockDim.x) {
            sWl[i] = Wl[i];
            sWr[i] = Wr[i];
        }
        __syncthreads();
        int n = blockIdx.x * blockDim.x + threadIdx.x;
        if (n >= N) return;
        float f[FIN];
#pragma unroll
        for (int g = 0; g < 10; ++g) f[g] = s0[n * PAD + g];
#pragma unroll
        for (int k = 0; k < 15; ++k) f[10 + k] = x1[n * 15 + k];
        float al[10], ar[10];
#pragma unroll
        for (int g = 0; g < 10; ++g) {
            float a = 0.f, r = 0.f;
#pragma unroll
            for (int k = 0; k < FIN; ++k) {
                a += f[k] * sWl[k * 10 + g];
                r += f[k] * sWr[k * 10 + g];
            }
            al[g] = a;
            ar[g] = r;
        }
        uint4 q0;
        q0.x = pk_bf16(al[0], al[1]);
        q0.y = pk_bf16(al[2], al[3]);
        q0.z = pk_bf16(al[4], al[5]);
        q0.w = pk_bf16(al[6], al[7]);
        uint4 q1;
        q1.x = pk_bf16(al[8], al[9]);
        q1.y = 0; q1.z = 0; q1.w = 0;
        uint4* pb = (uint4*)(XLb + (size_t)n * LP);
        pb[0] = q0;
        pb[1] = q1;
#pragma unroll
        for (int g = 0; g < 10; ++g) XR[n * PAD + g] = ar[g];
        XR[n * PAD + 10] = 0.f;
        XR[n * PAD + 11] = 0.f;
    } else {
        int i = ((int)blockIdx.x - NB) * 256 + (int)threadIdx.x;
        if (i < E) {
            int s = esrc[i], d = edst[i];
            sidx[rowptr[d] + pos[i]] = s;
        }
    }
}

// Transform (layers 2/3): xl = f @ Wl (packed bf16), xr = f @ Wr (fp32).
template <int NS>
__global__ void k_transform(const float* __restrict__ s0, const float* __restrict__ s1,
                            const float* __restrict__ s2, const float* __restrict__ x1,
                            const float* __restrict__ Wl, const float* __restrict__ Wr,
                            unsigned* __restrict__ XLb, float* __restrict__ XR, int N)
{
    constexpr int FIN = NS * 10 + 15;
    __shared__ float sWl[FIN * 10];
    __shared__ float sWr[FIN * 10];
    for (int i = threadIdx.x; i < FIN * 10; i += blockDim.x) {
        sWl[i] = Wl[i];
        sWr[i] = Wr[i];
    }
    __syncthreads();
    int n = blockIdx.x * blockDim.x + threadIdx.x;
    if (n >= N) return;
    float f[FIN];
    int o = 0;
    if constexpr (NS >= 1) {
#pragma unroll
        for (int g = 0; g < 10; ++g) f[o++] = s0[n * PAD + g];
    }
    if constexpr (NS >= 2) {
#pragma unroll
        for (int g = 0; g < 10; ++g) f[o++] = s1[n * PAD + g];
    }
    if constexpr (NS >= 3) {
#pragma unroll
        for (int g = 0; g < 10; ++g) f[o++] = s2[n * PAD + g];
    }
#pragma unroll
    for (int k = 0; k < 15; ++k) f[o++] = x1[n * 15 + k];
    float al[10], ar[10];
#pragma unroll
    for (int g = 0; g < 10; ++g) {
        float a = 0.f, r = 0.f;
#pragma unroll
        for (int k = 0; k < FIN; ++k) {
            a += f[k] * sWl[k * 10 + g];
            r += f[k] * sWr[k * 10 + g];
        }
        al[g] = a;
        ar[g] = r;
    }
    uint4 q0;
    q0.x = pk_bf16(al[0], al[1]);
    q0.y = pk_bf16(al[2], al[3]);
    q0.z = pk_bf16(al[4], al[5]);
    q0.w = pk_bf16(al[6], al[7]);
    uint4 q1;
    q1.x = pk_bf16(al[8], al[9]);
    q1.y = 0; q1.z = 0; q1.w = 0;
    uint4* pb = (uint4*)(XLb + (size_t)n * LP);
    pb[0] = q0;
    pb[1] = q1;
#pragma unroll
    for (int g = 0; g < 10; ++g) XR[n * PAD + g] = ar[g];
    XR[n * PAD + 10] = 0.f;
    XR[n * PAD + 11] = 0.f;
}

// CSR gather + edge softmax + finalize. 16 lanes per dst node, plain loop.
__global__ __launch_bounds__(256) void k_gather(
    const int* __restrict__ rowptr, const int* __restrict__ deg,
    const int* __restrict__ sidx,
    const unsigned* __restrict__ XLb, const float* __restrict__ XR,
    const float* __restrict__ att, const float* __restrict__ b,
    float* __restrict__ xo, int N)
{
    __shared__ float satt[10], sb[10];
    if (threadIdx.x < 10) { satt[threadIdx.x] = att[threadIdx.x]; sb[threadIdx.x] = b[threadIdx.x]; }
    __syncthreads();
    int node = blockIdx.x * 16 + (threadIdx.x >> 4);
    int l16 = threadIdx.x & 15;
    float acc[10];
#pragma unroll
    for (int g = 0; g < 10; ++g) acc[g] = 0.f;
    float den = 0.f;
    if (node < N) {
        const float4* pr = (const float4*)(XR + node * PAD);
        float4 r0 = pr[0], r1 = pr[1], r2 = pr[2];
        float xr[10] = {r0.x, r0.y, r0.z, r0.w, r1.x, r1.y, r1.z, r1.w, r2.x, r2.y};
        int start = rowptr[node];
        int dgr = deg[node];
        for (int j = l16; j < dgr; j += 16) {
            int s = sidx[start + j];
            const unsigned* pl = XLb + (size_t)s * LP;
            uint4 q = *(const uint4*)pl;
            unsigned q4 = pl[4];
            float xl[10] = {bf_lo(q.x), bf_hi(q.x), bf_lo(q.y), bf_hi(q.y),
                            bf_lo(q.z), bf_hi(q.z), bf_lo(q.w), bf_hi(q.w),
                            bf_lo(q4), bf_hi(q4)};
            float e = 0.f;
#pragma unroll
            for (int g = 0; g < 10; ++g) e += lrelu02(xl[g] + xr[g]) * satt[g];
            float ex = __expf(e);
#pragma unroll
            for (int g = 0; g < 10; ++g) acc[g] += ex * xl[g];
            den += ex;
        }
    }
#pragma unroll
    for (int off = 1; off < 16; off <<= 1) {
        den += __shfl_xor(den, off);
#pragma unroll
        for (int g = 0; g < 10; ++g) acc[g] += __shfl_xor(acc[g], off);
    }
    if (node < N && l16 == 0) {
        float inv = 1.f / den;
#pragma unroll
        for (int g = 0; g < 10; ++g)
            xo[node * PAD + g] = fmaxf(acc[g] * inv + sb[g], 0.f);
        xo[node * PAD + 10] = 0.f;
        xo[node * PAD + 11] = 0.f;
    }
}

// Fused: blocks [0,NB) -> value-head accumulation; [NB,..) -> policy head.
__global__ __launch_bounds__(256) void k_value_policy(
    const float* __restrict__ xc, const float* __restrict__ x1,
    const float* __restrict__ x2,
    const float* __restrict__ vtW, const float* __restrict__ vtb,
    const float* __restrict__ vaW, const float* __restrict__ vab,
    const float* __restrict__ vvW, const float* __restrict__ vvb,
    float* __restrict__ vsums,
    const int* __restrict__ asrc, const int* __restrict__ adst,
    const float* __restrict__ aarm,
    const int* __restrict__ dtgt, const float* __restrict__ darm,
    const float* __restrict__ atW, const float* __restrict__ atb,
    const float* __restrict__ dtW, const float* __restrict__ dtb,
    const float* __restrict__ oaW, const float* __restrict__ oab,
    const float* __restrict__ ovW, const float* __restrict__ ovb,
    float* __restrict__ pm, int NB, int N, int M)
{
    if ((int)blockIdx.x < NB) {
        __shared__ float sW[580];   // 29x20
        __shared__ float svv[200];  // 20x10
        __shared__ float sb20[20], sva[20], svvb[10], sx2[4];
        __shared__ float svab;
        __shared__ float sred[4][11];
        int t = threadIdx.x;
        for (int i = t; i < 580; i += blockDim.x) sW[i] = vtW[i];
        for (int i = t; i < 200; i += blockDim.x) svv[i] = vvW[i];
        if (t < 20) sb20[t] = vtb[t];
        if (t >= 32 && t < 52) sva[t - 32] = vaW[t - 32];
        if (t >= 64 && t < 74) svvb[t - 64] = vvb[t - 64];
        if (t >= 96 && t < 100) sx2[t - 96] = x2[t - 96];
        if (t == 128) svab = vab[0];
        __syncthreads();
        int n = blockIdx.x * blockDim.x + t;
        float w = 0.f;
        float wv[10];
#pragma unroll
        for (int c = 0; c < 10; ++c) wv[c] = 0.f;
        if (n < N) {
            float f[29];
#pragma unroll
            for (int k = 0; k < 10; ++k) f[k] = xc[n * PAD + k];
#pragma unroll
            for (int k = 0; k < 15; ++k) f[10 + k] = x1[n * 15 + k];
#pragma unroll
            for (int k = 0; k < 4; ++k) f[25 + k] = sx2[k];
            float v[20];
#pragma unroll
            for (int j = 0; j < 20; ++j) {
                float s = sb20[j];
#pragma unroll
                for (int k = 0; k < 29; ++k) s += f[k] * sW[k * 20 + j];
                v[j] = fmaxf(s, 0.f);
            }
            float sc = svab;
#pragma unroll
            for (int j = 0; j < 20; ++j) sc += v[j] * sva[j];
            w = __expf(sc);
#pragma unroll
            for (int c = 0; c < 10; ++c) {
                float t2 = svvb[c];
#pragma unroll
                for (int j = 0; j < 20; ++j) t2 += v[j] * svv[j * 10 + c];
                wv[c] = w * t2;
            }
        }
#pragma unroll
        for (int off = 32; off > 0; off >>= 1) {
            w += __shfl_xor(w, off);
#pragma unroll
            for (int c = 0; c < 10; ++c) wv[c] += __shfl_xor(wv[c], off);
        }
        int wave = t >> 6, lane = t & 63;
        if (lane == 0) {
            sred[wave][0] = w;
#pragma unroll
            for (int c = 0; c < 10; ++c) sred[wave][1 + c] = wv[c];
        }
        __syncthreads();
        if (t == 0) {
#pragma unroll
            for (int c = 0; c < 11; ++c) {
                float s = sred[0][c] + sred[1][c] + sred[2][c] + sred[3][c];
                atomicAdd(&vsums[c], s);
            }
        }
    } else {
        __shared__ float sat[960];  // 48x20
        __shared__ float sdt[460];  // 23x20
        __shared__ float satb[20], sdtb[20], soa[20], sov[20];
        __shared__ float soab, sovb;
        for (int i = threadIdx.x; i < 960; i += 256) sat[i] = atW[i];
        for (int i = threadIdx.x; i < 460; i += 256) sdt[i] = dtW[i];
        if (threadIdx.x < 20) {
            satb[threadIdx.x] = atb[threadIdx.x];
            sdtb[threadIdx.x] = dtb[threadIdx.x];
            soa[threadIdx.x] = oaW[threadIdx.x];
            sov[threadIdx.x] = ovW[threadIdx.x];
        }
        if (threadIdx.x == 32) { soab = oab[0]; sovb = ovb[0]; }
        __syncthreads();
        int wave = threadIdx.x >> 6, lane = threadIdx.x & 63;
        int m = ((int)blockIdx.x - NB) * 4 + wave;
        float asc = -1e30f, vsc = 0.f;
        if (m < M) {
            float ord[20];
            bool have = false;
            if (lane < 32) {
                int a = lane;
                int s = asrc[m * 32 + a], d = adst[m * 32 + a];
                float arm = aarm[m * 32 + a];
                float feat[48];
#pragma unroll
                for (int g = 0; g < 10; ++g) feat[g] = xc[s * PAD + g];
#pragma unroll
                for (int g = 0; g < 10; ++g) feat[10 + g] = xc[d * PAD + g];
#pragma unroll
                for (int k = 0; k < 12; ++k) feat[20 + k] = x1[s * 15 + 3 + k];
                float x1d[15];
#pragma unroll
                for (int k = 0; k < 15; ++k) x1d[k] = x1[d * 15 + k];
#pragma unroll
                for (int k = 0; k < 14; ++k) feat[32 + k] = x1d[1 + k];
                feat[46] = arm;
                feat[47] = 0.6f * arm - 0.7f * (x1d[3] + x1d[4]);
#pragma unroll
                for (int j = 0; j < 20; ++j) {
                    float s2 = satb[j];
#pragma unroll
                    for (int k = 0; k < 48; ++k) s2 += feat[k] * sat[k * 20 + j];
                    ord[j] = fmaxf(s2, 0.f);
                }
                have = true;
            } else if (lane < 48) {
                int dd = lane - 32;
                int tg = dtgt[m * 16 + dd];
                float arm = darm[m * 16 + dd];
                float feat[23];
#pragma unroll
                for (int g = 0; g < 10; ++g) feat[g] = xc[tg * PAD + g];
#pragma unroll
                for (int k = 0; k < 12; ++k) feat[10 + k] = x1[tg * 15 + 3 + k];
                feat[22] = arm;
#pragma unroll
                for (int j = 0; j < 20; ++j) {
                    float s2 = sdtb[j];
#pragma unroll
                    for (int k = 0; k < 23; ++k) s2 += feat[k] * sdt[k * 20 + j];
                    ord[j] = fmaxf(s2, 0.f);
                }
                have = true;
            }
            if (have) {
                asc = soab; vsc = sovb;
#pragma unroll
                for (int j = 0; j < 20; ++j) {
                    asc += ord[j] * soa[j];
                    vsc += ord[j] * sov[j];
                }
            }
        }
        float mx = asc;
#pragma unroll
        for (int off = 32; off > 0; off >>= 1) mx = fmaxf(mx, __shfl_xor(mx, off));
        float p = (asc > -1e29f) ? __expf(asc - mx) : 0.f;
        float num = p * vsc;
        float Z = p;
#pragma unroll
        for (int off = 32; off > 0; off >>= 1) {
            Z += __shfl_xor(Z, off);
            num += __shfl_xor(num, off);
        }
        if (m < M && lane == 0) pm[m] = num / Z;
    }
}

// out[1..M] = log_softmax(pm); thread 1023 also computes V -> out[0].
__global__ __launch_bounds__(1024) void k_final(
    const float* __restrict__ pm, const float* __restrict__ vsums,
    const float* __restrict__ vlW, const float* __restrict__ vlb,
    float* __restrict__ out, int M)
{
    __shared__ float red[16];
    __shared__ float sval;
    int t = threadIdx.x;
    int wave = t >> 6, lane = t & 63;
    if (t == 1023) {
        float inv = 1.f / vsums[0];
        float V = vlb[0];
#pragma unroll
        for (int j = 0; j < 10; ++j) V += fmaxf(vsums[1 + j] * inv, 0.f) * vlW[j];
        out[0] = tanhf(V);
    }
    float mx = -1e30f;
    for (int i = t; i < M; i += 1024) mx = fmaxf(mx, pm[i]);
#pragma unroll
    for (int off = 32; off > 0; off >>= 1) mx = fmaxf(mx, __shfl_xor(mx, off));
    if (lane == 0) red[wave] = mx;
    __syncthreads();
    if (t == 0) {
        float m2 = red[0];
        for (int i = 1; i < 16; ++i) m2 = fmaxf(m2, red[i]);
        sval = m2;
    }
    __syncthreads();
    float smax = sval;
    float sum = 0.f;
    for (int i = t; i < M; i += 1024) sum += __expf(pm[i] - smax);
#pragma unroll
    for (int off = 32; off > 0; off >>= 1) sum += __shfl_xor(sum, off);
    if (lane == 0) red[wave] = sum;
    __syncthreads();
    if (t == 0) {
        float s2 = 0.f;
        for (int i = 0; i < 16; ++i) s2 += red[i];
        sval = s2;
    }
    __syncthreads();
    float lse = smax + logf(sval);
    for (int i = t; i < M; i += 1024) out[1 + i] = pm[i] - lse;
}

extern "C" void kernel_launch(void* const* d_in, const int* in_sizes, int n_in,
                              void* d_out, int out_size, void* d_ws, size_t ws_size,
                              hipStream_t stream)
{
    const float* x1   = (const float*)d_in[0];
    const float* x2   = (const float*)d_in[1];
    const int*   edges = (const int*)d_in[2];
    const int*   asrc = (const int*)d_in[3];
    const int*   adst = (const int*)d_in[4];
    const float* aarm = (const float*)d_in[5];
    const int*   dtgt = (const int*)d_in[6];
    const float* darm = (const float*)d_in[7];
    const float* initW = (const float*)d_in[8];
    const float* initb = (const float*)d_in[9];
    const float* g1Wl = (const float*)d_in[10];
    const float* g1Wr = (const float*)d_in[11];
    const float* g1att = (const float*)d_in[12];
    const float* g1b = (const float*)d_in[13];
    const float* g2Wl = (const float*)d_in[14];
    const float* g2Wr = (const float*)d_in[15];
    const float* g2att = (const float*)d_in[16];
    const float* g2b = (const float*)d_in[17];
    const float* g3Wl = (const float*)d_in[18];
    const float* g3Wr = (const float*)d_in[19];
    const float* g3att = (const float*)d_in[20];
    const float* g3b = (const float*)d_in[21];
    const float* vtW = (const float*)d_in[22];
    const float* vtb = (const float*)d_in[23];
    const float* vaW = (const float*)d_in[24];
    const float* vab = (const float*)d_in[25];
    const float* vvW = (const float*)d_in[26];
    const float* vvb = (const float*)d_in[27];
    const float* vlW = (const float*)d_in[28];
    const float* vlb = (const float*)d_in[29];
    const float* atW = (const float*)d_in[30];
    const float* atb = (const float*)d_in[31];
    const float* dtW = (const float*)d_in[32];
    const float* dtb = (const float*)d_in[33];
    const float* oaW = (const float*)d_in[34];
    const float* oab = (const float*)d_in[35];
    const float* ovW = (const float*)d_in[36];
    const float* ovb = (const float*)d_in[37];

    const int N = in_sizes[0] / 15;
    const int E = in_sizes[2] / 2;
    const int M = in_sizes[3] / 32;
    const int Etot = E + N;

    float* ws = (float*)d_ws;
    size_t off = 0;
    float* XU = ws + off; off += (size_t)N * PAD;  // x_
    float* XA = ws + off; off += (size_t)N * PAD;
    float* XB = ws + off; off += (size_t)N * PAD;
    float* XC = ws + off; off += (size_t)N * PAD;
    unsigned* XLb = (unsigned*)(ws + off); off += (size_t)N * LP;
    float* XR = ws + off; off += (size_t)N * PAD;
    int* sidx = (int*)(ws + off); off += Etot;
    int* deg = (int*)(ws + off); off += N;
    int* rowptr = (int*)(ws + off); off += N + 8;
    int* bsum = (int*)(ws + off); off += 128;
    int* boff = (int*)(ws + off); off += 128;
    float* VS = ws + off; off += 16;
    float* PM = ws + off; off += M;
    // pos overlays XA..XC (3*N*PAD >= E); dead before first k_gather.
    int* pos = (int*)XA;

    float* outp = (float*)d_out;

    const int NB = (N + 255) / 256;
    const int HB = (E + 255) / 256;
    const int NG = (N + 15) / 16;       // gather: 16 lanes/node, 16 nodes/block
    const int NSC = (N + 1023) / 1024;  // scan blocks
    const int PB = (M + 3) / 4;         // policy blocks
    const int* esrc = edges;
    const int* edst = edges + E;

    k_degset<<<NB, 256, 0, stream>>>(deg, VS, N);
    k_init_hist<<<NB + HB, 256, 0, stream>>>(x1, initW, initb, XU, edst, E, deg, pos, NB, N);

    k_scan1<<<NSC, 1024, 0, stream>>>(deg, rowptr, bsum, N);
    k_scan2<<<1, 64, 0, stream>>>(bsum, boff, rowptr, NSC, N);
    k_scan3<<<NSC, 1024, 0, stream>>>(rowptr, boff, sidx, N);

    // scatter || transform layer 1
    k_scat_tr1<<<NB + HB, 256, 0, stream>>>(esrc, edst, E, rowptr, pos, sidx,
                                            XU, x1, g1Wl, g1Wr, XLb, XR, NB, N);
    k_gather<<<NG, 256, 0, stream>>>(rowptr, deg, sidx, XLb, XR, g1att, g1b, XA, N);

    // Layer 2: f = [xa, x_, x1]
    k_transform<2><<<NB, 256, 0, stream>>>(XA, XU, nullptr, x1, g2Wl, g2Wr, XLb, XR, N);
    k_gather<<<NG, 256, 0, stream>>>(rowptr, deg, sidx, XLb, XR, g2att, g2b, XB, N);

    // Layer 3: f = [xb, xa, x_, x1]
    k_transform<3><<<NB, 256, 0, stream>>>(XB, XA, XU, x1, g3Wl, g3Wr, XLb, XR, N);
    k_gather<<<NG, 256, 0, stream>>>(rowptr, deg, sidx, XLb, XR, g3att, g3b, XC, N);

    // value || policy
    k_value_policy<<<NB + PB, 256, 0, stream>>>(XC, x1, x2, vtW, vtb, vaW, vab,
                                                vvW, vvb, VS, asrc, adst, aarm,
                                                dtgt, darm, atW, atb, dtW, dtb,
                                                oaW, oab, ovW, ovb, PM, NB, N, M);
    k_final<<<1, 1024, 0, stream>>>(PM, VS, vlW, vlb, outp, M);
}

// Round 5
// 570.370 us; speedup vs baseline: 1.2118x; 1.1652x over previous
//
#include <hip/hip_runtime.h>
#include <math.h>

// Model8 R5: bucketed CSR build. Global atomics 3.2M -> ~630K:
//  A1: per-block LDS hist over 782 dst-buckets (dst>>7) + 1 global atomic per
//      (block,bucket);  bscan: bucket-level scan;  A2: re-hist + reserve via
//      gcur + place packed edges (src | dlocal<<17);  B: one block per bucket
//      builds exact CSR rows in LDS (self-loop slot 0), coalesced sidx writes.
// Fusions: init||A1, transform1||B. Gather: 16 lanes/node + batch-2 ILP.

#define PAD 12   // padded row stride for fp32 [N,10] arrays
#define LP 8     // XLb packed row stride in u32 (32B)
#define MAXB 784 // LDS bucket array size (>= (N+127)/128)

__device__ __forceinline__ float lrelu02(float v) { return v > 0.f ? v : 0.2f * v; }

__device__ __forceinline__ unsigned pk_bf16(float a, float b)
{
    unsigned ua = __float_as_uint(a), ub = __float_as_uint(b);
    ua += 0x7fffu + ((ua >> 16) & 1u);
    ub += 0x7fffu + ((ub >> 16) & 1u);
    return (ua >> 16) | (ub & 0xffff0000u);
}
__device__ __forceinline__ float bf_lo(unsigned u) { return __uint_as_float(u << 16); }
__device__ __forceinline__ float bf_hi(unsigned u) { return __uint_as_float(u & 0xffff0000u); }

__global__ void k_zero(int* __restrict__ gbucket, float* __restrict__ vsums, int NBK)
{
    int t = threadIdx.x;
    if (t < NBK) gbucket[t] = 0;
    if (t < 16) vsums[t] = 0.f;
}

// Fused: blocks [0,PA) -> phase A1 (bucket counts); [PA,..) -> x_ = relu(x1@W+b).
__global__ __launch_bounds__(256) void k_a1_init(
    const int* __restrict__ edst, int E, int* __restrict__ gbucket,
    const float* __restrict__ x1, const float* __restrict__ W,
    const float* __restrict__ b, float* __restrict__ xo, int PA, int N, int NBK)
{
    if ((int)blockIdx.x < PA) {
        __shared__ int h[MAXB];
        for (int j = threadIdx.x; j < NBK; j += 256) h[j] = 0;
        __syncthreads();
        int base = blockIdx.x * 8192;
        for (int k = 0; k < 32; ++k) {
            int i = base + k * 256 + threadIdx.x;
            if (i < E) atomicAdd(&h[edst[i] >> 7], 1);
        }
        __syncthreads();
        for (int j = threadIdx.x; j < NBK; j += 256) {
            int c = h[j];
            if (c) atomicAdd(&gbucket[j], c);
        }
    } else {
        __shared__ float sW[150];
        __shared__ float sb[10];
        int t = threadIdx.x;
        if (t < 150) sW[t] = W[t];
        if (t < 10) sb[t] = b[t];
        __syncthreads();
        int n = ((int)blockIdx.x - PA) * 256 + t;
        if (n >= N) return;
        float f[15];
#pragma unroll
        for (int k = 0; k < 15; ++k) f[k] = x1[n * 15 + k];
#pragma unroll
        for (int g = 0; g < 10; ++g) {
            float s = sb[g];
#pragma unroll
            for (int k = 0; k < 15; ++k) s += f[k] * sW[k * 10 + g];
            xo[n * PAD + g] = fmaxf(s, 0.f);
        }
        xo[n * PAD + 10] = 0.f;
        xo[n * PAD + 11] = 0.f;
    }
}

// Bucket-level exclusive scans: pbase (edges), sbase (edges + live nodes).
// Also rowptr[N] = Etot and gcur = pbase copy.
__global__ __launch_bounds__(1024) void k_bscan(
    const int* __restrict__ gbucket, int* __restrict__ pbase,
    int* __restrict__ sbase, int* __restrict__ gcur,
    int* __restrict__ rowptr, int N, int NBK)
{
    __shared__ int w1[16], w2[16];
    int t = threadIdx.x, lane = t & 63, wv = t >> 6;
    int cE = 0, cT = 0;
    if (t < NBK) {
        cE = gbucket[t];
        int nin = N - (t << 7);
        nin = nin < 0 ? 0 : (nin > 128 ? 128 : nin);
        cT = cE + nin;
    }
    int i1 = cE, i2 = cT;
#pragma unroll
    for (int off = 1; off < 64; off <<= 1) {
        int u1 = __shfl_up(i1, off), u2 = __shfl_up(i2, off);
        if (lane >= off) { i1 += u1; i2 += u2; }
    }
    if (lane == 63) { w1[wv] = i1; w2[wv] = i2; }
    __syncthreads();
    int o1 = 0, o2 = 0;
    for (int k = 0; k < wv; ++k) { o1 += w1[k]; o2 += w2[k]; }
    i1 += o1; i2 += o2;
    if (t < NBK) {
        int pb = i1 - cE, sb = i2 - cT;
        pbase[t] = pb;
        sbase[t] = sb;
        gcur[t] = pb;
        if (t == NBK - 1) { pbase[NBK] = i1; sbase[NBK] = i2; rowptr[N] = i2; }
    }
}

// Phase A2: re-hist, reserve pairs-space per (block,bucket) via gcur, place
// packed edges. pairs[slot] = src | (dst&127)<<17.
__global__ __launch_bounds__(256) void k_a2(
    const int* __restrict__ esrc, const int* __restrict__ edst, int E,
    int* __restrict__ gcur, unsigned* __restrict__ pairs, int NBK)
{
    __shared__ int h[MAXB];
    __shared__ int bs[MAXB];
    for (int j = threadIdx.x; j < NBK; j += 256) h[j] = 0;
    __syncthreads();
    int base = blockIdx.x * 8192;
    for (int k = 0; k < 32; ++k) {
        int i = base + k * 256 + threadIdx.x;
        if (i < E) atomicAdd(&h[edst[i] >> 7], 1);
    }
    __syncthreads();
    for (int j = threadIdx.x; j < NBK; j += 256) {
        int c = h[j];
        bs[j] = c ? atomicAdd(&gcur[j], c) : 0;
        h[j] = 0;
    }
    __syncthreads();
    for (int k = 0; k < 32; ++k) {
        int i = base + k * 256 + threadIdx.x;
        if (i < E) {
            int d = edst[i], s = esrc[i];
            int bkt = d >> 7;
            int off = atomicAdd(&h[bkt], 1);
            pairs[bs[bkt] + off] = (unsigned)s | ((unsigned)(d & 127) << 17);
        }
    }
}

// Fused: blocks [0,NBK) -> per-bucket CSR build; [NBK,..) -> transform layer1.
__global__ __launch_bounds__(256) void k_b_tr1(
    const unsigned* __restrict__ pairs, const int* __restrict__ pbase,
    const int* __restrict__ sbase, int* __restrict__ rowptr,
    int* __restrict__ deg, int* __restrict__ sidx, int N, int NBK,
    const float* __restrict__ s0a, const float* __restrict__ x1,
    const float* __restrict__ Wl, const float* __restrict__ Wr,
    unsigned* __restrict__ XLb, float* __restrict__ XR, int NB)
{
    if ((int)blockIdx.x < NBK) {
        __shared__ int cnt[128];
        __shared__ int cur[128];
        __shared__ int wtot;
        int t = threadIdx.x;
        if (t < 128) cnt[t] = 0;
        __syncthreads();
        int b = blockIdx.x, p0 = pbase[b], p1 = pbase[b + 1], n0 = b << 7;
        int nn = N - n0; nn = nn < 0 ? 0 : (nn > 128 ? 128 : nn);
        for (int i = p0 + t; i < p1; i += 256) atomicAdd(&cnt[pairs[i] >> 17], 1);
        __syncthreads();
        int x = 0, incl = 0;
        if (t < 128) {
            x = cnt[t] + (t < nn ? 1 : 0);
            incl = x;
            int lane = t & 63;
#pragma unroll
            for (int off = 1; off < 64; off <<= 1) {
                int u = __shfl_up(incl, off);
                if (lane >= off) incl += u;
            }
            if (t == 63) wtot = incl;
        }
        __syncthreads();
        int sb = sbase[b];
        if (t < 128) {
            if (t >= 64) incl += wtot;
            int st = incl - x;  // exclusive
            if (t < nn) {
                int r = sb + st;
                rowptr[n0 + t] = r;
                deg[n0 + t] = cnt[t] + 1;
                sidx[r] = n0 + t;        // self-loop slot 0
                cur[t] = st + 1;         // next free offset within bucket
            } else {
                cur[t] = st;
            }
        }
        __syncthreads();
        for (int i = p0 + t; i < p1; i += 256) {
            unsigned w = pairs[i];
            int l = w >> 17, s = w & 0x1FFFF;
            int off = atomicAdd(&cur[l], 1);
            sidx[sb + off] = s;
        }
    } else {
        constexpr int FIN = 25;
        __shared__ float sWl[FIN * 10];
        __shared__ float sWr[FIN * 10];
        for (int i = threadIdx.x; i < FIN * 10; i += 256) {
            sWl[i] = Wl[i];
            sWr[i] = Wr[i];
        }
        __syncthreads();
        int n = ((int)blockIdx.x - NBK) * 256 + (int)threadIdx.x;
        if (n >= N) return;
        float f[FIN];
#pragma unroll
        for (int g = 0; g < 10; ++g) f[g] = s0a[n * PAD + g];
#pragma unroll
        for (int k = 0; k < 15; ++k) f[10 + k] = x1[n * 15 + k];
        float al[10], ar[10];
#pragma unroll
        for (int g = 0; g < 10; ++g) {
            float a = 0.f, r = 0.f;
#pragma unroll
            for (int k = 0; k < FIN; ++k) {
                a += f[k] * sWl[k * 10 + g];
                r += f[k] * sWr[k * 10 + g];
            }
            al[g] = a;
            ar[g] = r;
        }
        uint4 q0;
        q0.x = pk_bf16(al[0], al[1]);
        q0.y = pk_bf16(al[2], al[3]);
        q0.z = pk_bf16(al[4], al[5]);
        q0.w = pk_bf16(al[6], al[7]);
        uint4 q1;
        q1.x = pk_bf16(al[8], al[9]);
        q1.y = 0; q1.z = 0; q1.w = 0;
        uint4* pb = (uint4*)(XLb + (size_t)n * LP);
        pb[0] = q0;
        pb[1] = q1;
#pragma unroll
        for (int g = 0; g < 10; ++g) XR[n * PAD + g] = ar[g];
        XR[n * PAD + 10] = 0.f;
        XR[n * PAD + 11] = 0.f;
    }
}

// Transform (layers 2/3).
template <int NS>
__global__ void k_transform(const float* __restrict__ s0, const float* __restrict__ s1,
                            const float* __restrict__ s2, const float* __restrict__ x1,
                            const float* __restrict__ Wl, const float* __restrict__ Wr,
                            unsigned* __restrict__ XLb, float* __restrict__ XR, int N)
{
    constexpr int FIN = NS * 10 + 15;
    __shared__ float sWl[FIN * 10];
    __shared__ float sWr[FIN * 10];
    for (int i = threadIdx.x; i < FIN * 10; i += blockDim.x) {
        sWl[i] = Wl[i];
        sWr[i] = Wr[i];
    }
    __syncthreads();
    int n = blockIdx.x * blockDim.x + threadIdx.x;
    if (n >= N) return;
    float f[FIN];
    int o = 0;
    if constexpr (NS >= 1) {
#pragma unroll
        for (int g = 0; g < 10; ++g) f[o++] = s0[n * PAD + g];
    }
    if constexpr (NS >= 2) {
#pragma unroll
        for (int g = 0; g < 10; ++g) f[o++] = s1[n * PAD + g];
    }
    if constexpr (NS >= 3) {
#pragma unroll
        for (int g = 0; g < 10; ++g) f[o++] = s2[n * PAD + g];
    }
#pragma unroll
    for (int k = 0; k < 15; ++k) f[o++] = x1[n * 15 + k];
    float al[10], ar[10];
#pragma unroll
    for (int g = 0; g < 10; ++g) {
        float a = 0.f, r = 0.f;
#pragma unroll
        for (int k = 0; k < FIN; ++k) {
            a += f[k] * sWl[k * 10 + g];
            r += f[k] * sWr[k * 10 + g];
        }
        al[g] = a;
        ar[g] = r;
    }
    uint4 q0;
    q0.x = pk_bf16(al[0], al[1]);
    q0.y = pk_bf16(al[2], al[3]);
    q0.z = pk_bf16(al[4], al[5]);
    q0.w = pk_bf16(al[6], al[7]);
    uint4 q1;
    q1.x = pk_bf16(al[8], al[9]);
    q1.y = 0; q1.z = 0; q1.w = 0;
    uint4* pb = (uint4*)(XLb + (size_t)n * LP);
    pb[0] = q0;
    pb[1] = q1;
#pragma unroll
    for (int g = 0; g < 10; ++g) XR[n * PAD + g] = ar[g];
    XR[n * PAD + 10] = 0.f;
    XR[n * PAD + 11] = 0.f;
}

// CSR gather + edge softmax + finalize. 16 lanes/node, batch-2 ILP.
__global__ __launch_bounds__(256) void k_gather(
    const int* __restrict__ rowptr, const int* __restrict__ deg,
    const int* __restrict__ sidx,
    const unsigned* __restrict__ XLb, const float* __restrict__ XR,
    const float* __restrict__ att, const float* __restrict__ b,
    float* __restrict__ xo, int N)
{
    __shared__ float satt[10], sb[10];
    if (threadIdx.x < 10) { satt[threadIdx.x] = att[threadIdx.x]; sb[threadIdx.x] = b[threadIdx.x]; }
    __syncthreads();
    int node = blockIdx.x * 16 + (threadIdx.x >> 4);
    int l16 = threadIdx.x & 15;
    float acc[10];
#pragma unroll
    for (int g = 0; g < 10; ++g) acc[g] = 0.f;
    float den = 0.f;
    if (node < N) {
        const float4* pr = (const float4*)(XR + node * PAD);
        float4 r0 = pr[0], r1 = pr[1], r2 = pr[2];
        float xr[10] = {r0.x, r0.y, r0.z, r0.w, r1.x, r1.y, r1.z, r1.w, r2.x, r2.y};
        int start = rowptr[node];
        int dgr = deg[node];
        int j = l16;
        while (j + 16 < dgr) {
            int s0 = sidx[start + j];
            int s1 = sidx[start + j + 16];
            const unsigned* pl0 = XLb + (size_t)s0 * LP;
            const unsigned* pl1 = XLb + (size_t)s1 * LP;
            uint4 qa = *(const uint4*)pl0;
            unsigned qa4 = pl0[4];
            uint4 qb = *(const uint4*)pl1;
            unsigned qb4 = pl1[4];
            float xa[10] = {bf_lo(qa.x), bf_hi(qa.x), bf_lo(qa.y), bf_hi(qa.y),
                            bf_lo(qa.z), bf_hi(qa.z), bf_lo(qa.w), bf_hi(qa.w),
                            bf_lo(qa4), bf_hi(qa4)};
            float xb[10] = {bf_lo(qb.x), bf_hi(qb.x), bf_lo(qb.y), bf_hi(qb.y),
                            bf_lo(qb.z), bf_hi(qb.z), bf_lo(qb.w), bf_hi(qb.w),
                            bf_lo(qb4), bf_hi(qb4)};
            float ea = 0.f, eb = 0.f;
#pragma unroll
            for (int g = 0; g < 10; ++g) {
                ea += lrelu02(xa[g] + xr[g]) * satt[g];
                eb += lrelu02(xb[g] + xr[g]) * satt[g];
            }
            float exa = __expf(ea), exb = __expf(eb);
#pragma unroll
            for (int g = 0; g < 10; ++g) acc[g] += exa * xa[g] + exb * xb[g];
            den += exa + exb;
            j += 32;
        }
        if (j < dgr) {
            int s = sidx[start + j];
            const unsigned* pl = XLb + (size_t)s * LP;
            uint4 q = *(const uint4*)pl;
            unsigned q4 = pl[4];
            float xl[10] = {bf_lo(q.x), bf_hi(q.x), bf_lo(q.y), bf_hi(q.y),
                            bf_lo(q.z), bf_hi(q.z), bf_lo(q.w), bf_hi(q.w),
                            bf_lo(q4), bf_hi(q4)};
            float e = 0.f;
#pragma unroll
            for (int g = 0; g < 10; ++g) e += lrelu02(xl[g] + xr[g]) * satt[g];
            float ex = __expf(e);
#pragma unroll
            for (int g = 0; g < 10; ++g) acc[g] += ex * xl[g];
            den += ex;
        }
    }
#pragma unroll
    for (int off = 1; off < 16; off <<= 1) {
        den += __shfl_xor(den, off);
#pragma unroll
        for (int g = 0; g < 10; ++g) acc[g] += __shfl_xor(acc[g], off);
    }
    if (node < N && l16 == 0) {
        float inv = 1.f / den;
#pragma unroll
        for (int g = 0; g < 10; ++g)
            xo[node * PAD + g] = fmaxf(acc[g] * inv + sb[g], 0.f);
        xo[node * PAD + 10] = 0.f;
        xo[node * PAD + 11] = 0.f;
    }
}

// Fused: blocks [0,NB) -> value-head accumulation; [NB,..) -> policy head.
__global__ __launch_bounds__(256) void k_value_policy(
    const float* __restrict__ xc, const float* __restrict__ x1,
    const float* __restrict__ x2,
    const float* __restrict__ vtW, const float* __restrict__ vtb,
    const float* __restrict__ vaW, const float* __restrict__ vab,
    const float* __restrict__ vvW, const float* __restrict__ vvb,
    float* __restrict__ vsums,
    const int* __restrict__ asrc, const int* __restrict__ adst,
    const float* __restrict__ aarm,
    const int* __restrict__ dtgt, const float* __restrict__ darm,
    const float* __restrict__ atW, const float* __restrict__ atb,
    const float* __restrict__ dtW, const float* __restrict__ dtb,
    const float* __restrict__ oaW, const float* __restrict__ oab,
    const float* __restrict__ ovW, const float* __restrict__ ovb,
    float* __restrict__ pm, int NB, int N, int M)
{
    if ((int)blockIdx.x < NB) {
        __shared__ float sW[580];
        __shared__ float svv[200];
        __shared__ float sb20[20], sva[20], svvb[10], sx2[4];
        __shared__ float svab;
        __shared__ float sred[4][11];
        int t = threadIdx.x;
        for (int i = t; i < 580; i += blockDim.x) sW[i] = vtW[i];
        for (int i = t; i < 200; i += blockDim.x) svv[i] = vvW[i];
        if (t < 20) sb20[t] = vtb[t];
        if (t >= 32 && t < 52) sva[t - 32] = vaW[t - 32];
        if (t >= 64 && t < 74) svvb[t - 64] = vvb[t - 64];
        if (t >= 96 && t < 100) sx2[t - 96] = x2[t - 96];
        if (t == 128) svab = vab[0];
        __syncthreads();
        int n = blockIdx.x * blockDim.x + t;
        float w = 0.f;
        float wv[10];
#pragma unroll
        for (int c = 0; c < 10; ++c) wv[c] = 0.f;
        if (n < N) {
            float f[29];
#pragma unroll
            for (int k = 0; k < 10; ++k) f[k] = xc[n * PAD + k];
#pragma unroll
            for (int k = 0; k < 15; ++k) f[10 + k] = x1[n * 15 + k];
#pragma unroll
            for (int k = 0; k < 4; ++k) f[25 + k] = sx2[k];
            float v[20];
#pragma unroll
            for (int j = 0; j < 20; ++j) {
                float s = sb20[j];
#pragma unroll
                for (int k = 0; k < 29; ++k) s += f[k] * sW[k * 20 + j];
                v[j] = fmaxf(s, 0.f);
            }
            float sc = svab;
#pragma unroll
            for (int j = 0; j < 20; ++j) sc += v[j] * sva[j];
            w = __expf(sc);
#pragma unroll
            for (int c = 0; c < 10; ++c) {
                float t2 = svvb[c];
#pragma unroll
                for (int j = 0; j < 20; ++j) t2 += v[j] * svv[j * 10 + c];
                wv[c] = w * t2;
            }
        }
#pragma unroll
        for (int off = 32; off > 0; off >>= 1) {
            w += __shfl_xor(w, off);
#pragma unroll
            for (int c = 0; c < 10; ++c) wv[c] += __shfl_xor(wv[c], off);
        }
        int wave = t >> 6, lane = t & 63;
        if (lane == 0) {
            sred[wave][0] = w;
#pragma unroll
            for (int c = 0; c < 10; ++c) sred[wave][1 + c] = wv[c];
        }
        __syncthreads();
        if (t == 0) {
#pragma unroll
            for (int c = 0; c < 11; ++c) {
                float s = sred[0][c] + sred[1][c] + sred[2][c] + sred[3][c];
                atomicAdd(&vsums[c], s);
            }
        }
    } else {
        __shared__ float sat[960];
        __shared__ float sdt[460];
        __shared__ float satb[20], sdtb[20], soa[20], sov[20];
        __shared__ float soab, sovb;
        for (int i = threadIdx.x; i < 960; i += 256) sat[i] = atW[i];
        for (int i = threadIdx.x; i < 460; i += 256) sdt[i] = dtW[i];
        if (threadIdx.x < 20) {
            satb[threadIdx.x] = atb[threadIdx.x];
            sdtb[threadIdx.x] = dtb[threadIdx.x];
            soa[threadIdx.x] = oaW[threadIdx.x];
            sov[threadIdx.x] = ovW[threadIdx.x];
        }
        if (threadIdx.x == 32) { soab = oab[0]; sovb = ovb[0]; }
        __syncthreads();
        int wave = threadIdx.x >> 6, lane = threadIdx.x & 63;
        int m = ((int)blockIdx.x - NB) * 4 + wave;
        float asc = -1e30f, vsc = 0.f;
        if (m < M) {
            float ord[20];
            bool have = false;
            if (lane < 32) {
                int a = lane;
                int s = asrc[m * 32 + a], d = adst[m * 32 + a];
                float arm = aarm[m * 32 + a];
                float feat[48];
#pragma unroll
                for (int g = 0; g < 10; ++g) feat[g] = xc[s * PAD + g];
#pragma unroll
                for (int g = 0; g < 10; ++g) feat[10 + g] = xc[d * PAD + g];
#pragma unroll
                for (int k = 0; k < 12; ++k) feat[20 + k] = x1[s * 15 + 3 + k];
                float x1d[15];
#pragma unroll
                for (int k = 0; k < 15; ++k) x1d[k] = x1[d * 15 + k];
#pragma unroll
                for (int k = 0; k < 14; ++k) feat[32 + k] = x1d[1 + k];
                feat[46] = arm;
                feat[47] = 0.6f * arm - 0.7f * (x1d[3] + x1d[4]);
#pragma unroll
                for (int j = 0; j < 20; ++j) {
                    float s2 = satb[j];
#pragma unroll
                    for (int k = 0; k < 48; ++k) s2 += feat[k] * sat[k * 20 + j];
                    ord[j] = fmaxf(s2, 0.f);
                }
                have = true;
            } else if (lane < 48) {
                int dd = lane - 32;
                int tg = dtgt[m * 16 + dd];
                float arm = darm[m * 16 + dd];
                float feat[23];
#pragma unroll
                for (int g = 0; g < 10; ++g) feat[g] = xc[tg * PAD + g];
#pragma unroll
                for (int k = 0; k < 12; ++k) feat[10 + k] = x1[tg * 15 + 3 + k];
                feat[22] = arm;
#pragma unroll
                for (int j = 0; j < 20; ++j) {
                    float s2 = sdtb[j];
#pragma unroll
                    for (int k = 0; k < 23; ++k) s2 += feat[k] * sdt[k * 20 + j];
                    ord[j] = fmaxf(s2, 0.f);
                }
                have = true;
            }
            if (have) {
                asc = soab; vsc = sovb;
#pragma unroll
                for (int j = 0; j < 20; ++j) {
                    asc += ord[j] * soa[j];
                    vsc += ord[j] * sov[j];
                }
            }
        }
        float mx = asc;
#pragma unroll
        for (int off = 32; off > 0; off >>= 1) mx = fmaxf(mx, __shfl_xor(mx, off));
        float p = (asc > -1e29f) ? __expf(asc - mx) : 0.f;
        float num = p * vsc;
        float Z = p;
#pragma unroll
        for (int off = 32; off > 0; off >>= 1) {
            Z += __shfl_xor(Z, off);
            num += __shfl_xor(num, off);
        }
        if (m < M && lane == 0) pm[m] = num / Z;
    }
}

// out[1..M] = log_softmax(pm); thread 1023 computes V -> out[0].
__global__ __launch_bounds__(1024) void k_final(
    const float* __restrict__ pm, const float* __restrict__ vsums,
    const float* __restrict__ vlW, const float* __restrict__ vlb,
    float* __restrict__ out, int M)
{
    __shared__ float red[16];
    __shared__ float sval;
    int t = threadIdx.x;
    int wave = t >> 6, lane = t & 63;
    if (t == 1023) {
        float inv = 1.f / vsums[0];
        float V = vlb[0];
#pragma unroll
        for (int j = 0; j < 10; ++j) V += fmaxf(vsums[1 + j] * inv, 0.f) * vlW[j];
        out[0] = tanhf(V);
    }
    float mx = -1e30f;
    for (int i = t; i < M; i += 1024) mx = fmaxf(mx, pm[i]);
#pragma unroll
    for (int off = 32; off > 0; off >>= 1) mx = fmaxf(mx, __shfl_xor(mx, off));
    if (lane == 0) red[wave] = mx;
    __syncthreads();
    if (t == 0) {
        float m2 = red[0];
        for (int i = 1; i < 16; ++i) m2 = fmaxf(m2, red[i]);
        sval = m2;
    }
    __syncthreads();
    float smax = sval;
    float sum = 0.f;
    for (int i = t; i < M; i += 1024) sum += __expf(pm[i] - smax);
#pragma unroll
    for (int off = 32; off > 0; off >>= 1) sum += __shfl_xor(sum, off);
    if (lane == 0) red[wave] = sum;
    __syncthreads();
    if (t == 0) {
        float s2 = 0.f;
        for (int i = 0; i < 16; ++i) s2 += red[i];
        sval = s2;
    }
    __syncthreads();
    float lse = smax + logf(sval);
    for (int i = t; i < M; i += 1024) out[1 + i] = pm[i] - lse;
}

extern "C" void kernel_launch(void* const* d_in, const int* in_sizes, int n_in,
                              void* d_out, int out_size, void* d_ws, size_t ws_size,
                              hipStream_t stream)
{
    const float* x1   = (const float*)d_in[0];
    const float* x2   = (const float*)d_in[1];
    const int*   edges = (const int*)d_in[2];
    const int*   asrc = (const int*)d_in[3];
    const int*   adst = (const int*)d_in[4];
    const float* aarm = (const float*)d_in[5];
    const int*   dtgt = (const int*)d_in[6];
    const float* darm = (const float*)d_in[7];
    const float* initW = (const float*)d_in[8];
    const float* initb = (const float*)d_in[9];
    const float* g1Wl = (const float*)d_in[10];
    const float* g1Wr = (const float*)d_in[11];
    const float* g1att = (const float*)d_in[12];
    const float* g1b = (const float*)d_in[13];
    const float* g2Wl = (const float*)d_in[14];
    const float* g2Wr = (const float*)d_in[15];
    const float* g2att = (const float*)d_in[16];
    const float* g2b = (const float*)d_in[17];
    const float* g3Wl = (const float*)d_in[18];
    const float* g3Wr = (const float*)d_in[19];
    const float* g3att = (const float*)d_in[20];
    const float* g3b = (const float*)d_in[21];
    const float* vtW = (const float*)d_in[22];
    const float* vtb = (const float*)d_in[23];
    const float* vaW = (const float*)d_in[24];
    const float* vab = (const float*)d_in[25];
    const float* vvW = (const float*)d_in[26];
    const float* vvb = (const float*)d_in[27];
    const float* vlW = (const float*)d_in[28];
    const float* vlb = (const float*)d_in[29];
    const float* atW = (const float*)d_in[30];
    const float* atb = (const float*)d_in[31];
    const float* dtW = (const float*)d_in[32];
    const float* dtb = (const float*)d_in[33];
    const float* oaW = (const float*)d_in[34];
    const float* oab = (const float*)d_in[35];
    const float* ovW = (const float*)d_in[36];
    const float* ovb = (const float*)d_in[37];

    const int N = in_sizes[0] / 15;
    const int E = in_sizes[2] / 2;
    const int M = in_sizes[3] / 32;
    const int Etot = E + N;
    const int NBK = (N + 127) >> 7;  // buckets of 128 nodes (N < 2^17 assumed)

    float* ws = (float*)d_ws;
    size_t off = 0;
    float* XU = ws + off; off += (size_t)N * PAD;
    float* XA = ws + off; off += (size_t)N * PAD;
    float* XB = ws + off; off += (size_t)N * PAD;
    float* XC = ws + off; off += (size_t)N * PAD;
    unsigned* XLb = (unsigned*)(ws + off); off += (size_t)N * LP;
    float* XR = ws + off; off += (size_t)N * PAD;
    int* sidx = (int*)(ws + off); off += Etot;
    unsigned* pairs = (unsigned*)(ws + off); off += E;
    int* deg = (int*)(ws + off); off += N;
    int* rowptr = (int*)(ws + off); off += N + 8;
    int* gbucket = (int*)(ws + off); off += MAXB + 8;
    int* pbase = (int*)(ws + off); off += MAXB + 8;
    int* sbase = (int*)(ws + off); off += MAXB + 8;
    int* gcur = (int*)(ws + off); off += MAXB + 8;
    float* VS = ws + off; off += 16;
    float* PM = ws + off; off += M;

    float* outp = (float*)d_out;

    const int NB = (N + 255) / 256;
    const int PA = (E + 8191) / 8192;   // phase-A blocks (8192 edges each)
    const int NG = (N + 15) / 16;
    const int PB = (M + 3) / 4;
    const int* esrc = edges;
    const int* edst = edges + E;

    k_zero<<<1, 1024, 0, stream>>>(gbucket, VS, NBK);
    k_a1_init<<<PA + NB, 256, 0, stream>>>(edst, E, gbucket, x1, initW, initb, XU, PA, N, NBK);
    k_bscan<<<1, 1024, 0, stream>>>(gbucket, pbase, sbase, gcur, rowptr, N, NBK);
    k_a2<<<PA, 256, 0, stream>>>(esrc, edst, E, gcur, pairs, NBK);
    k_b_tr1<<<NBK + NB, 256, 0, stream>>>(pairs, pbase, sbase, rowptr, deg, sidx, N, NBK,
                                          XU, x1, g1Wl, g1Wr, XLb, XR, NB);
    k_gather<<<NG, 256, 0, stream>>>(rowptr, deg, sidx, XLb, XR, g1att, g1b, XA, N);

    k_transform<2><<<NB, 256, 0, stream>>>(XA, XU, nullptr, x1, g2Wl, g2Wr, XLb, XR, N);
    k_gather<<<NG, 256, 0, stream>>>(rowptr, deg, sidx, XLb, XR, g2att, g2b, XB, N);

    k_transform<3><<<NB, 256, 0, stream>>>(XB, XA, XU, x1, g3Wl, g3Wr, XLb, XR, N);
    k_gather<<<NG, 256, 0, stream>>>(rowptr, deg, sidx, XLb, XR, g3att, g3b, XC, N);

    k_value_policy<<<NB + PB, 256, 0, stream>>>(XC, x1, x2, vtW, vtb, vaW, vab,
                                                vvW, vvb, VS, asrc, adst, aarm,
                                                dtgt, darm, atW, atb, dtW, dtb,
                                                oaW, oab, ovW, ovb, PM, NB, N, M);
    k_final<<<1, 1024, 0, stream>>>(PM, VS, vlW, vlb, outp, M);
}

// Round 6
// 409.138 us; speedup vs baseline: 1.6893x; 1.3941x over previous
//
#include <hip/hip_runtime.h>
#include <math.h>

// Model8 R6: kill scratch spills. R5 top-5 = k_transform @93us, VGPR=64 with
// ~80-reg live set, FETCH 114MB/WRITE 179MB (ideal 28MB) -> spilled f[] array.
// Fix: streaming-k matvecs (no feature staging arrays), wave-uniform weights
// read directly from global (scalar cache) instead of LDS, float4 row IO.

#define PAD 12   // padded row stride for fp32 [N,10] arrays (48B, 16B-aligned)
#define LP 8     // XLb packed row stride in u32 (32B)
#define MAXB 784 // LDS bucket array size (>= (N+127)/128)

__device__ __forceinline__ float lrelu02(float v) { return v > 0.f ? v : 0.2f * v; }

__device__ __forceinline__ unsigned pk_bf16(float a, float b)
{
    unsigned ua = __float_as_uint(a), ub = __float_as_uint(b);
    ua += 0x7fffu + ((ua >> 16) & 1u);
    ub += 0x7fffu + ((ub >> 16) & 1u);
    return (ua >> 16) | (ub & 0xffff0000u);
}
__device__ __forceinline__ float bf_lo(unsigned u) { return __uint_as_float(u << 16); }
__device__ __forceinline__ float bf_hi(unsigned u) { return __uint_as_float(u & 0xffff0000u); }

__global__ void k_zero(int* __restrict__ gbucket, float* __restrict__ vsums, int NBK)
{
    int t = threadIdx.x;
    if (t < NBK) gbucket[t] = 0;
    if (t < 16) vsums[t] = 0.f;
}

// Streaming transform body: al/ar accumulators only, weights via uniform
// scalar reads (unrolled constant indices), feature rows via float4.
template <int NS>
__device__ __forceinline__ void transform_body(
    int n, const float* __restrict__ s0, const float* __restrict__ s1,
    const float* __restrict__ s2, const float* __restrict__ x1,
    const float* __restrict__ Wl, const float* __restrict__ Wr,
    unsigned* __restrict__ XLb, float* __restrict__ XR)
{
    float al[10], ar[10];
#pragma unroll
    for (int g = 0; g < 10; ++g) { al[g] = 0.f; ar[g] = 0.f; }
    int o = 0;
#define TB_BLOCK(SP)                                                        \
    {                                                                       \
        const float4* pr = (const float4*)((SP) + n * PAD);                 \
        float4 v0 = pr[0], v1 = pr[1], v2 = pr[2];                          \
        float fv[10] = {v0.x, v0.y, v0.z, v0.w, v1.x, v1.y, v1.z, v1.w,     \
                        v2.x, v2.y};                                        \
        _Pragma("unroll") for (int k = 0; k < 10; ++k)                      \
        {                                                                   \
            _Pragma("unroll") for (int g = 0; g < 10; ++g)                  \
            {                                                               \
                al[g] += fv[k] * Wl[(o + k) * 10 + g];                      \
                ar[g] += fv[k] * Wr[(o + k) * 10 + g];                      \
            }                                                               \
        }                                                                   \
        o += 10;                                                            \
    }
    if constexpr (NS >= 1) TB_BLOCK(s0)
    if constexpr (NS >= 2) TB_BLOCK(s1)
    if constexpr (NS >= 3) TB_BLOCK(s2)
#undef TB_BLOCK
#pragma unroll
    for (int k = 0; k < 15; ++k) {
        float fv = x1[n * 15 + k];
#pragma unroll
        for (int g = 0; g < 10; ++g) {
            al[g] += fv * Wl[(o + k) * 10 + g];
            ar[g] += fv * Wr[(o + k) * 10 + g];
        }
    }
    uint4 q0;
    q0.x = pk_bf16(al[0], al[1]);
    q0.y = pk_bf16(al[2], al[3]);
    q0.z = pk_bf16(al[4], al[5]);
    q0.w = pk_bf16(al[6], al[7]);
    uint4 q1;
    q1.x = pk_bf16(al[8], al[9]);
    q1.y = 0; q1.z = 0; q1.w = 0;
    uint4* pb = (uint4*)(XLb + (size_t)n * LP);
    pb[0] = q0;
    pb[1] = q1;
    float4* po = (float4*)(XR + n * PAD);
    po[0] = make_float4(ar[0], ar[1], ar[2], ar[3]);
    po[1] = make_float4(ar[4], ar[5], ar[6], ar[7]);
    po[2] = make_float4(ar[8], ar[9], 0.f, 0.f);
}

// Fused: blocks [0,PA) -> phase A1 (bucket counts); [PA,..) -> x_ = relu(x1@W+b).
__global__ __launch_bounds__(256) void k_a1_init(
    const int* __restrict__ edst, int E, int* __restrict__ gbucket,
    const float* __restrict__ x1, const float* __restrict__ W,
    const float* __restrict__ b, float* __restrict__ xo, int PA, int N, int NBK)
{
    if ((int)blockIdx.x < PA) {
        __shared__ int h[MAXB];
        for (int j = threadIdx.x; j < NBK; j += 256) h[j] = 0;
        __syncthreads();
        int base = blockIdx.x * 8192;
        for (int k = 0; k < 32; ++k) {
            int i = base + k * 256 + threadIdx.x;
            if (i < E) atomicAdd(&h[edst[i] >> 7], 1);
        }
        __syncthreads();
        for (int j = threadIdx.x; j < NBK; j += 256) {
            int c = h[j];
            if (c) atomicAdd(&gbucket[j], c);
        }
    } else {
        int n = ((int)blockIdx.x - PA) * 256 + (int)threadIdx.x;
        if (n >= N) return;
        float acc[10];
#pragma unroll
        for (int g = 0; g < 10; ++g) acc[g] = b[g];
#pragma unroll
        for (int k = 0; k < 15; ++k) {
            float fv = x1[n * 15 + k];
#pragma unroll
            for (int g = 0; g < 10; ++g) acc[g] += fv * W[k * 10 + g];
        }
        float4* po = (float4*)(xo + n * PAD);
        po[0] = make_float4(fmaxf(acc[0], 0.f), fmaxf(acc[1], 0.f),
                            fmaxf(acc[2], 0.f), fmaxf(acc[3], 0.f));
        po[1] = make_float4(fmaxf(acc[4], 0.f), fmaxf(acc[5], 0.f),
                            fmaxf(acc[6], 0.f), fmaxf(acc[7], 0.f));
        po[2] = make_float4(fmaxf(acc[8], 0.f), fmaxf(acc[9], 0.f), 0.f, 0.f);
    }
}

// Bucket-level exclusive scans: pbase (edges), sbase (edges + live nodes).
__global__ __launch_bounds__(1024) void k_bscan(
    const int* __restrict__ gbucket, int* __restrict__ pbase,
    int* __restrict__ sbase, int* __restrict__ gcur,
    int* __restrict__ rowptr, int N, int NBK)
{
    __shared__ int w1[16], w2[16];
    int t = threadIdx.x, lane = t & 63, wv = t >> 6;
    int cE = 0, cT = 0;
    if (t < NBK) {
        cE = gbucket[t];
        int nin = N - (t << 7);
        nin = nin < 0 ? 0 : (nin > 128 ? 128 : nin);
        cT = cE + nin;
    }
    int i1 = cE, i2 = cT;
#pragma unroll
    for (int off = 1; off < 64; off <<= 1) {
        int u1 = __shfl_up(i1, off), u2 = __shfl_up(i2, off);
        if (lane >= off) { i1 += u1; i2 += u2; }
    }
    if (lane == 63) { w1[wv] = i1; w2[wv] = i2; }
    __syncthreads();
    int o1 = 0, o2 = 0;
    for (int k = 0; k < wv; ++k) { o1 += w1[k]; o2 += w2[k]; }
    i1 += o1; i2 += o2;
    if (t < NBK) {
        int pb = i1 - cE, sb = i2 - cT;
        pbase[t] = pb;
        sbase[t] = sb;
        gcur[t] = pb;
        if (t == NBK - 1) { pbase[NBK] = i1; sbase[NBK] = i2; rowptr[N] = i2; }
    }
}

// Phase A2: re-hist, reserve pairs-space per (block,bucket) via gcur, place
// packed edges. pairs[slot] = src | (dst&127)<<17.
__global__ __launch_bounds__(256) void k_a2(
    const int* __restrict__ esrc, const int* __restrict__ edst, int E,
    int* __restrict__ gcur, unsigned* __restrict__ pairs, int NBK)
{
    __shared__ int h[MAXB];
    __shared__ int bs[MAXB];
    for (int j = threadIdx.x; j < NBK; j += 256) h[j] = 0;
    __syncthreads();
    int base = blockIdx.x * 8192;
    for (int k = 0; k < 32; ++k) {
        int i = base + k * 256 + threadIdx.x;
        if (i < E) atomicAdd(&h[edst[i] >> 7], 1);
    }
    __syncthreads();
    for (int j = threadIdx.x; j < NBK; j += 256) {
        int c = h[j];
        bs[j] = c ? atomicAdd(&gcur[j], c) : 0;
        h[j] = 0;
    }
    __syncthreads();
    for (int k = 0; k < 32; ++k) {
        int i = base + k * 256 + threadIdx.x;
        if (i < E) {
            int d = edst[i], s = esrc[i];
            int bkt = d >> 7;
            int off = atomicAdd(&h[bkt], 1);
            pairs[bs[bkt] + off] = (unsigned)s | ((unsigned)(d & 127) << 17);
        }
    }
}

// Fused: blocks [0,NBK) -> per-bucket CSR build; [NBK,..) -> transform layer1.
__global__ __launch_bounds__(256) void k_b_tr1(
    const unsigned* __restrict__ pairs, const int* __restrict__ pbase,
    const int* __restrict__ sbase, int* __restrict__ rowptr,
    int* __restrict__ deg, int* __restrict__ sidx, int N, int NBK,
    const float* __restrict__ s0a, const float* __restrict__ x1,
    const float* __restrict__ Wl, const float* __restrict__ Wr,
    unsigned* __restrict__ XLb, float* __restrict__ XR, int NB)
{
    if ((int)blockIdx.x < NBK) {
        __shared__ int cnt[128];
        __shared__ int cur[128];
        __shared__ int wtot;
        int t = threadIdx.x;
        if (t < 128) cnt[t] = 0;
        __syncthreads();
        int b = blockIdx.x, p0 = pbase[b], p1 = pbase[b + 1], n0 = b << 7;
        int nn = N - n0; nn = nn < 0 ? 0 : (nn > 128 ? 128 : nn);
        for (int i = p0 + t; i < p1; i += 256) atomicAdd(&cnt[pairs[i] >> 17], 1);
        __syncthreads();
        int x = 0, incl = 0;
        if (t < 128) {
            x = cnt[t] + (t < nn ? 1 : 0);
            incl = x;
            int lane = t & 63;
#pragma unroll
            for (int off = 1; off < 64; off <<= 1) {
                int u = __shfl_up(incl, off);
                if (lane >= off) incl += u;
            }
            if (t == 63) wtot = incl;
        }
        __syncthreads();
        int sb = sbase[b];
        if (t < 128) {
            if (t >= 64) incl += wtot;
            int st = incl - x;  // exclusive
            if (t < nn) {
                int r = sb + st;
                rowptr[n0 + t] = r;
                deg[n0 + t] = cnt[t] + 1;
                sidx[r] = n0 + t;        // self-loop slot 0
                cur[t] = st + 1;
            } else {
                cur[t] = st;
            }
        }
        __syncthreads();
        for (int i = p0 + t; i < p1; i += 256) {
            unsigned w = pairs[i];
            int l = w >> 17, s = w & 0x1FFFF;
            int off = atomicAdd(&cur[l], 1);
            sidx[sb + off] = s;
        }
    } else {
        int n = ((int)blockIdx.x - NBK) * 256 + (int)threadIdx.x;
        if (n >= N) return;
        transform_body<1>(n, s0a, nullptr, nullptr, x1, Wl, Wr, XLb, XR);
    }
}

// Transform (layers 2/3), streaming-k, no LDS.
template <int NS>
__global__ __launch_bounds__(256) void k_transform(
    const float* __restrict__ s0, const float* __restrict__ s1,
    const float* __restrict__ s2, const float* __restrict__ x1,
    const float* __restrict__ Wl, const float* __restrict__ Wr,
    unsigned* __restrict__ XLb, float* __restrict__ XR, int N)
{
    int n = blockIdx.x * blockDim.x + threadIdx.x;
    if (n >= N) return;
    transform_body<NS>(n, s0, s1, s2, x1, Wl, Wr, XLb, XR);
}

// CSR gather + edge softmax + finalize. 16 lanes/node, batch-2 ILP.
__global__ __launch_bounds__(256) void k_gather(
    const int* __restrict__ rowptr, const int* __restrict__ deg,
    const int* __restrict__ sidx,
    const unsigned* __restrict__ XLb, const float* __restrict__ XR,
    const float* __restrict__ att, const float* __restrict__ b,
    float* __restrict__ xo, int N)
{
    int node = blockIdx.x * 16 + (threadIdx.x >> 4);
    int l16 = threadIdx.x & 15;
    float acc[10];
#pragma unroll
    for (int g = 0; g < 10; ++g) acc[g] = 0.f;
    float den = 0.f;
    float satt[10];
#pragma unroll
    for (int g = 0; g < 10; ++g) satt[g] = att[g];  // uniform scalar loads
    if (node < N) {
        const float4* pr = (const float4*)(XR + node * PAD);
        float4 r0 = pr[0], r1 = pr[1], r2 = pr[2];
        float xr[10] = {r0.x, r0.y, r0.z, r0.w, r1.x, r1.y, r1.z, r1.w, r2.x, r2.y};
        int start = rowptr[node];
        int dgr = deg[node];
        int j = l16;
        while (j + 16 < dgr) {
            int s0 = sidx[start + j];
            int s1 = sidx[start + j + 16];
            const unsigned* pl0 = XLb + (size_t)s0 * LP;
            const unsigned* pl1 = XLb + (size_t)s1 * LP;
            uint4 qa = *(const uint4*)pl0;
            unsigned qa4 = pl0[4];
            uint4 qb = *(const uint4*)pl1;
            unsigned qb4 = pl1[4];
            float xa[10] = {bf_lo(qa.x), bf_hi(qa.x), bf_lo(qa.y), bf_hi(qa.y),
                            bf_lo(qa.z), bf_hi(qa.z), bf_lo(qa.w), bf_hi(qa.w),
                            bf_lo(qa4), bf_hi(qa4)};
            float xb[10] = {bf_lo(qb.x), bf_hi(qb.x), bf_lo(qb.y), bf_hi(qb.y),
                            bf_lo(qb.z), bf_hi(qb.z), bf_lo(qb.w), bf_hi(qb.w),
                            bf_lo(qb4), bf_hi(qb4)};
            float ea = 0.f, eb = 0.f;
#pragma unroll
            for (int g = 0; g < 10; ++g) {
                ea += lrelu02(xa[g] + xr[g]) * satt[g];
                eb += lrelu02(xb[g] + xr[g]) * satt[g];
            }
            float exa = __expf(ea), exb = __expf(eb);
#pragma unroll
            for (int g = 0; g < 10; ++g) acc[g] += exa * xa[g] + exb * xb[g];
            den += exa + exb;
            j += 32;
        }
        if (j < dgr) {
            int s = sidx[start + j];
            const unsigned* pl = XLb + (size_t)s * LP;
            uint4 q = *(const uint4*)pl;
            unsigned q4 = pl[4];
            float xl[10] = {bf_lo(q.x), bf_hi(q.x), bf_lo(q.y), bf_hi(q.y),
                            bf_lo(q.z), bf_hi(q.z), bf_lo(q.w), bf_hi(q.w),
                            bf_lo(q4), bf_hi(q4)};
            float e = 0.f;
#pragma unroll
            for (int g = 0; g < 10; ++g) e += lrelu02(xl[g] + xr[g]) * satt[g];
            float ex = __expf(e);
#pragma unroll
            for (int g = 0; g < 10; ++g) acc[g] += ex * xl[g];
            den += ex;
        }
    }
#pragma unroll
    for (int off = 1; off < 16; off <<= 1) {
        den += __shfl_xor(den, off);
#pragma unroll
        for (int g = 0; g < 10; ++g) acc[g] += __shfl_xor(acc[g], off);
    }
    if (node < N && l16 == 0) {
        float inv = 1.f / den;
        float r[10];
#pragma unroll
        for (int g = 0; g < 10; ++g) r[g] = fmaxf(acc[g] * inv + b[g], 0.f);
        float4* po = (float4*)(xo + node * PAD);
        po[0] = make_float4(r[0], r[1], r[2], r[3]);
        po[1] = make_float4(r[4], r[5], r[6], r[7]);
        po[2] = make_float4(r[8], r[9], 0.f, 0.f);
    }
}

// Fused: blocks [0,NB) -> value-head accumulation; [NB,..) -> policy head.
// Both branches streaming-k (no feature arrays, no weight LDS).
__global__ __launch_bounds__(256) void k_value_policy(
    const float* __restrict__ xc, const float* __restrict__ x1,
    const float* __restrict__ x2,
    const float* __restrict__ vtW, const float* __restrict__ vtb,
    const float* __restrict__ vaW, const float* __restrict__ vab,
    const float* __restrict__ vvW, const float* __restrict__ vvb,
    float* __restrict__ vsums,
    const int* __restrict__ asrc, const int* __restrict__ adst,
    const float* __restrict__ aarm,
    const int* __restrict__ dtgt, const float* __restrict__ darm,
    const float* __restrict__ atW, const float* __restrict__ atb,
    const float* __restrict__ dtW, const float* __restrict__ dtb,
    const float* __restrict__ oaW, const float* __restrict__ oab,
    const float* __restrict__ ovW, const float* __restrict__ ovb,
    float* __restrict__ pm, int NB, int N, int M)
{
    if ((int)blockIdx.x < NB) {
        __shared__ float sred[4][11];
        int t = threadIdx.x;
        int n = blockIdx.x * blockDim.x + t;
        float w = 0.f;
        float wv[10];
#pragma unroll
        for (int c = 0; c < 10; ++c) wv[c] = 0.f;
        if (n < N) {
            float v[20];
#pragma unroll
            for (int j = 0; j < 20; ++j) v[j] = vtb[j];
            {
                const float4* pc = (const float4*)(xc + n * PAD);
                float4 c0 = pc[0], c1 = pc[1], c2 = pc[2];
                float fv[10] = {c0.x, c0.y, c0.z, c0.w, c1.x, c1.y, c1.z, c1.w,
                                c2.x, c2.y};
#pragma unroll
                for (int k = 0; k < 10; ++k)
#pragma unroll
                    for (int j = 0; j < 20; ++j) v[j] += fv[k] * vtW[k * 20 + j];
            }
#pragma unroll
            for (int k = 0; k < 15; ++k) {
                float fv = x1[n * 15 + k];
#pragma unroll
                for (int j = 0; j < 20; ++j) v[j] += fv * vtW[(10 + k) * 20 + j];
            }
#pragma unroll
            for (int k = 0; k < 4; ++k) {
                float fv = x2[k];
#pragma unroll
                for (int j = 0; j < 20; ++j) v[j] += fv * vtW[(25 + k) * 20 + j];
            }
            float sc = vab[0];
#pragma unroll
            for (int j = 0; j < 20; ++j) {
                v[j] = fmaxf(v[j], 0.f);
                sc += v[j] * vaW[j];
            }
            w = __expf(sc);
#pragma unroll
            for (int c = 0; c < 10; ++c) {
                float t2 = vvb[c];
#pragma unroll
                for (int j = 0; j < 20; ++j) t2 += v[j] * vvW[j * 10 + c];
                wv[c] = w * t2;
            }
        }
#pragma unroll
        for (int off = 32; off > 0; off >>= 1) {
            w += __shfl_xor(w, off);
#pragma unroll
            for (int c = 0; c < 10; ++c) wv[c] += __shfl_xor(wv[c], off);
        }
        int wave = t >> 6, lane = t & 63;
        if (lane == 0) {
            sred[wave][0] = w;
#pragma unroll
            for (int c = 0; c < 10; ++c) sred[wave][1 + c] = wv[c];
        }
        __syncthreads();
        if (t == 0) {
#pragma unroll
            for (int c = 0; c < 11; ++c) {
                float s = sred[0][c] + sred[1][c] + sred[2][c] + sred[3][c];
                atomicAdd(&vsums[c], s);
            }
        }
    } else {
        int wave = threadIdx.x >> 6, lane = threadIdx.x & 63;
        int m = ((int)blockIdx.x - NB) * 4 + wave;
        float asc = -1e30f, vsc = 0.f;
        if (m < M) {
            float ord[20];
            bool have = false;
            if (lane < 32) {
                int a = lane;
                int s = asrc[m * 32 + a], d = adst[m * 32 + a];
                float arm = aarm[m * 32 + a];
#pragma unroll
                for (int j = 0; j < 20; ++j) ord[j] = atb[j];
                {
                    const float4* pc = (const float4*)(xc + s * PAD);
                    float4 c0 = pc[0], c1 = pc[1], c2 = pc[2];
                    float fv[10] = {c0.x, c0.y, c0.z, c0.w, c1.x, c1.y, c1.z,
                                    c1.w, c2.x, c2.y};
#pragma unroll
                    for (int k = 0; k < 10; ++k)
#pragma unroll
                        for (int j = 0; j < 20; ++j)
                            ord[j] += fv[k] * atW[k * 20 + j];
                }
                {
                    const float4* pc = (const float4*)(xc + d * PAD);
                    float4 c0 = pc[0], c1 = pc[1], c2 = pc[2];
                    float fv[10] = {c0.x, c0.y, c0.z, c0.w, c1.x, c1.y, c1.z,
                                    c1.w, c2.x, c2.y};
#pragma unroll
                    for (int k = 0; k < 10; ++k)
#pragma unroll
                        for (int j = 0; j < 20; ++j)
                            ord[j] += fv[k] * atW[(10 + k) * 20 + j];
                }
#pragma unroll
                for (int k = 0; k < 12; ++k) {
                    float fv = x1[s * 15 + 3 + k];
#pragma unroll
                    for (int j = 0; j < 20; ++j)
                        ord[j] += fv * atW[(20 + k) * 20 + j];
                }
                float d3 = 0.f, d4 = 0.f;
#pragma unroll
                for (int k = 0; k < 14; ++k) {
                    float fv = x1[d * 15 + 1 + k];
                    if (k == 2) d3 = fv;
                    if (k == 3) d4 = fv;
#pragma unroll
                    for (int j = 0; j < 20; ++j)
                        ord[j] += fv * atW[(32 + k) * 20 + j];
                }
                float extra = 0.6f * arm - 0.7f * (d3 + d4);
#pragma unroll
                for (int j = 0; j < 20; ++j)
                    ord[j] += arm * atW[46 * 20 + j] + extra * atW[47 * 20 + j];
                have = true;
            } else if (lane < 48) {
                int dd = lane - 32;
                int tg = dtgt[m * 16 + dd];
                float arm = darm[m * 16 + dd];
#pragma unroll
                for (int j = 0; j < 20; ++j) ord[j] = dtb[j];
                {
                    const float4* pc = (const float4*)(xc + tg * PAD);
                    float4 c0 = pc[0], c1 = pc[1], c2 = pc[2];
                    float fv[10] = {c0.x, c0.y, c0.z, c0.w, c1.x, c1.y, c1.z,
                                    c1.w, c2.x, c2.y};
#pragma unroll
                    for (int k = 0; k < 10; ++k)
#pragma unroll
                        for (int j = 0; j < 20; ++j)
                            ord[j] += fv[k] * dtW[k * 20 + j];
                }
#pragma unroll
                for (int k = 0; k < 12; ++k) {
                    float fv = x1[tg * 15 + 3 + k];
#pragma unroll
                    for (int j = 0; j < 20; ++j)
                        ord[j] += fv * dtW[(10 + k) * 20 + j];
                }
#pragma unroll
                for (int j = 0; j < 20; ++j) ord[j] += arm * dtW[22 * 20 + j];
                have = true;
            }
            if (have) {
                asc = oab[0]; vsc = ovb[0];
#pragma unroll
                for (int j = 0; j < 20; ++j) {
                    float oj = fmaxf(ord[j], 0.f);
                    asc += oj * oaW[j];
                    vsc += oj * ovW[j];
                }
            }
        }
        float mx = asc;
#pragma unroll
        for (int off = 32; off > 0; off >>= 1) mx = fmaxf(mx, __shfl_xor(mx, off));
        float p = (asc > -1e29f) ? __expf(asc - mx) : 0.f;
        float num = p * vsc;
        float Z = p;
#pragma unroll
        for (int off = 32; off > 0; off >>= 1) {
            Z += __shfl_xor(Z, off);
            num += __shfl_xor(num, off);
        }
        if (m < M && lane == 0) pm[m] = num / Z;
    }
}

// out[1..M] = log_softmax(pm); thread 1023 computes V -> out[0].
__global__ __launch_bounds__(1024) void k_final(
    const float* __restrict__ pm, const float* __restrict__ vsums,
    const float* __restrict__ vlW, const float* __restrict__ vlb,
    float* __restrict__ out, int M)
{
    __shared__ float red[16];
    __shared__ float sval;
    int t = threadIdx.x;
    int wave = t >> 6, lane = t & 63;
    if (t == 1023) {
        float inv = 1.f / vsums[0];
        float V = vlb[0];
#pragma unroll
        for (int j = 0; j < 10; ++j) V += fmaxf(vsums[1 + j] * inv, 0.f) * vlW[j];
        out[0] = tanhf(V);
    }
    float mx = -1e30f;
    for (int i = t; i < M; i += 1024) mx = fmaxf(mx, pm[i]);
#pragma unroll
    for (int off = 32; off > 0; off >>= 1) mx = fmaxf(mx, __shfl_xor(mx, off));
    if (lane == 0) red[wave] = mx;
    __syncthreads();
    if (t == 0) {
        float m2 = red[0];
        for (int i = 1; i < 16; ++i) m2 = fmaxf(m2, red[i]);
        sval = m2;
    }
    __syncthreads();
    float smax = sval;
    float sum = 0.f;
    for (int i = t; i < M; i += 1024) sum += __expf(pm[i] - smax);
#pragma unroll
    for (int off = 32; off > 0; off >>= 1) sum += __shfl_xor(sum, off);
    if (lane == 0) red[wave] = sum;
    __syncthreads();
    if (t == 0) {
        float s2 = 0.f;
        for (int i = 0; i < 16; ++i) s2 += red[i];
        sval = s2;
    }
    __syncthreads();
    float lse = smax + logf(sval);
    for (int i = t; i < M; i += 1024) out[1 + i] = pm[i] - lse;
}

extern "C" void kernel_launch(void* const* d_in, const int* in_sizes, int n_in,
                              void* d_out, int out_size, void* d_ws, size_t ws_size,
                              hipStream_t stream)
{
    const float* x1   = (const float*)d_in[0];
    const float* x2   = (const float*)d_in[1];
    const int*   edges = (const int*)d_in[2];
    const int*   asrc = (const int*)d_in[3];
    const int*   adst = (const int*)d_in[4];
    const float* aarm = (const float*)d_in[5];
    const int*   dtgt = (const int*)d_in[6];
    const float* darm = (const float*)d_in[7];
    const float* initW = (const float*)d_in[8];
    const float* initb = (const float*)d_in[9];
    const float* g1Wl = (const float*)d_in[10];
    const float* g1Wr = (const float*)d_in[11];
    const float* g1att = (const float*)d_in[12];
    const float* g1b = (const float*)d_in[13];
    const float* g2Wl = (const float*)d_in[14];
    const float* g2Wr = (const float*)d_in[15];
    const float* g2att = (const float*)d_in[16];
    const float* g2b = (const float*)d_in[17];
    const float* g3Wl = (const float*)d_in[18];
    const float* g3Wr = (const float*)d_in[19];
    const float* g3att = (const float*)d_in[20];
    const float* g3b = (const float*)d_in[21];
    const float* vtW = (const float*)d_in[22];
    const float* vtb = (const float*)d_in[23];
    const float* vaW = (const float*)d_in[24];
    const float* vab = (const float*)d_in[25];
    const float* vvW = (const float*)d_in[26];
    const float* vvb = (const float*)d_in[27];
    const float* vlW = (const float*)d_in[28];
    const float* vlb = (const float*)d_in[29];
    const float* atW = (const float*)d_in[30];
    const float* atb = (const float*)d_in[31];
    const float* dtW = (const float*)d_in[32];
    const float* dtb = (const float*)d_in[33];
    const float* oaW = (const float*)d_in[34];
    const float* oab = (const float*)d_in[35];
    const float* ovW = (const float*)d_in[36];
    const float* ovb = (const float*)d_in[37];

    const int N = in_sizes[0] / 15;
    const int E = in_sizes[2] / 2;
    const int M = in_sizes[3] / 32;
    const int Etot = E + N;
    const int NBK = (N + 127) >> 7;

    float* ws = (float*)d_ws;
    size_t off = 0;
    float* XU = ws + off; off += (size_t)N * PAD;
    float* XA = ws + off; off += (size_t)N * PAD;
    float* XB = ws + off; off += (size_t)N * PAD;
    float* XC = ws + off; off += (size_t)N * PAD;
    unsigned* XLb = (unsigned*)(ws + off); off += (size_t)N * LP;
    float* XR = ws + off; off += (size_t)N * PAD;
    int* sidx = (int*)(ws + off); off += Etot;
    unsigned* pairs = (unsigned*)(ws + off); off += E;
    int* deg = (int*)(ws + off); off += N;
    int* rowptr = (int*)(ws + off); off += N + 8;
    int* gbucket = (int*)(ws + off); off += MAXB + 8;
    int* pbase = (int*)(ws + off); off += MAXB + 8;
    int* sbase = (int*)(ws + off); off += MAXB + 8;
    int* gcur = (int*)(ws + off); off += MAXB + 8;
    float* VS = ws + off; off += 16;
    float* PM = ws + off; off += M;

    float* outp = (float*)d_out;

    const int NB = (N + 255) / 256;
    const int PA = (E + 8191) / 8192;
    const int NG = (N + 15) / 16;
    const int PB = (M + 3) / 4;
    const int* esrc = edges;
    const int* edst = edges + E;

    k_zero<<<1, 1024, 0, stream>>>(gbucket, VS, NBK);
    k_a1_init<<<PA + NB, 256, 0, stream>>>(edst, E, gbucket, x1, initW, initb, XU, PA, N, NBK);
    k_bscan<<<1, 1024, 0, stream>>>(gbucket, pbase, sbase, gcur, rowptr, N, NBK);
    k_a2<<<PA, 256, 0, stream>>>(esrc, edst, E, gcur, pairs, NBK);
    k_b_tr1<<<NBK + NB, 256, 0, stream>>>(pairs, pbase, sbase, rowptr, deg, sidx, N, NBK,
                                          XU, x1, g1Wl, g1Wr, XLb, XR, NB);
    k_gather<<<NG, 256, 0, stream>>>(rowptr, deg, sidx, XLb, XR, g1att, g1b, XA, N);

    k_transform<2><<<NB, 256, 0, stream>>>(XA, XU, nullptr, x1, g2Wl, g2Wr, XLb, XR, N);
    k_gather<<<NG, 256, 0, stream>>>(rowptr, deg, sidx, XLb, XR, g2att, g2b, XB, N);

    k_transform<3><<<NB, 256, 0, stream>>>(XB, XA, XU, x1, g3Wl, g3Wr, XLb, XR, N);
    k_gather<<<NG, 256, 0, stream>>>(rowptr, deg, sidx, XLb, XR, g3att, g3b, XC, N);

    k_value_policy<<<NB + PB, 256, 0, stream>>>(XC, x1, x2, vtW, vtb, vaW, vab,
                                                vvW, vvb, VS, asrc, adst, aarm,
                                                dtgt, darm, atW, atb, dtW, dtb,
                                                oaW, oab, ovW, ovb, PM, NB, N, M);
    k_final<<<1, 1024, 0, stream>>>(PM, VS, vlW, vlb, outp, M);
}

// Round 7
// 395.043 us; speedup vs baseline: 1.7496x; 1.0357x over previous
//
#include <hip/hip_runtime.h>
#include <math.h>

// Model8 R7: exact-placement edge partition. R6 top-5 = k_a2 (~70us,
// occupancy 11%, 3 serial passes/block + reservation atomics). Now:
// A1 stores pos[i] (within-chunk-bucket slot) + per-chunk bucket counts;
// global scan over cntg gives exact bases; A2 = 1 parallel pass, no LDS,
// no atomics. pbase/sbase derive from bases (k_bscan/k_zero deleted).

#define PAD 12    // padded row stride for fp32 [N,10] arrays (48B)
#define LP 8      // XLb packed row stride in u32 (32B)
#define MAXB 784  // LDS bucket array size (>= (N+127)/128)
#define CHK 8192  // edges per A1 chunk

__device__ __forceinline__ float lrelu02(float v) { return v > 0.f ? v : 0.2f * v; }

__device__ __forceinline__ unsigned pk_bf16(float a, float b)
{
    unsigned ua = __float_as_uint(a), ub = __float_as_uint(b);
    ua += 0x7fffu + ((ua >> 16) & 1u);
    ub += 0x7fffu + ((ub >> 16) & 1u);
    return (ua >> 16) | (ub & 0xffff0000u);
}
__device__ __forceinline__ float bf_lo(unsigned u) { return __uint_as_float(u << 16); }
__device__ __forceinline__ float bf_hi(unsigned u) { return __uint_as_float(u & 0xffff0000u); }

// Streaming transform body (R6): accumulators only, uniform weight reads.
template <int NS>
__device__ __forceinline__ void transform_body(
    int n, const float* __restrict__ s0, const float* __restrict__ s1,
    const float* __restrict__ s2, const float* __restrict__ x1,
    const float* __restrict__ Wl, const float* __restrict__ Wr,
    unsigned* __restrict__ XLb, float* __restrict__ XR)
{
    float al[10], ar[10];
#pragma unroll
    for (int g = 0; g < 10; ++g) { al[g] = 0.f; ar[g] = 0.f; }
    int o = 0;
#define TB_BLOCK(SP)                                                        \
    {                                                                       \
        const float4* pr = (const float4*)((SP) + n * PAD);                 \
        float4 v0 = pr[0], v1 = pr[1], v2 = pr[2];                          \
        float fv[10] = {v0.x, v0.y, v0.z, v0.w, v1.x, v1.y, v1.z, v1.w,     \
                        v2.x, v2.y};                                        \
        _Pragma("unroll") for (int k = 0; k < 10; ++k)                      \
        {                                                                   \
            _Pragma("unroll") for (int g = 0; g < 10; ++g)                  \
            {                                                               \
                al[g] += fv[k] * Wl[(o + k) * 10 + g];                      \
                ar[g] += fv[k] * Wr[(o + k) * 10 + g];                      \
            }                                                               \
        }                                                                   \
        o += 10;                                                            \
    }
    if constexpr (NS >= 1) TB_BLOCK(s0)
    if constexpr (NS >= 2) TB_BLOCK(s1)
    if constexpr (NS >= 3) TB_BLOCK(s2)
#undef TB_BLOCK
#pragma unroll
    for (int k = 0; k < 15; ++k) {
        float fv = x1[n * 15 + k];
#pragma unroll
        for (int g = 0; g < 10; ++g) {
            al[g] += fv * Wl[(o + k) * 10 + g];
            ar[g] += fv * Wr[(o + k) * 10 + g];
        }
    }
    uint4 q0;
    q0.x = pk_bf16(al[0], al[1]);
    q0.y = pk_bf16(al[2], al[3]);
    q0.z = pk_bf16(al[4], al[5]);
    q0.w = pk_bf16(al[6], al[7]);
    uint4 q1;
    q1.x = pk_bf16(al[8], al[9]);
    q1.y = 0; q1.z = 0; q1.w = 0;
    uint4* pb = (uint4*)(XLb + (size_t)n * LP);
    pb[0] = q0;
    pb[1] = q1;
    float4* po = (float4*)(XR + n * PAD);
    po[0] = make_float4(ar[0], ar[1], ar[2], ar[3]);
    po[1] = make_float4(ar[4], ar[5], ar[6], ar[7]);
    po[2] = make_float4(ar[8], ar[9], 0.f, 0.f);
}

// Fused: blocks [0,PA) -> A1 (LDS hist -> pos[i] + cntg column);
// [PA,..) -> x_ = relu(x1@W+b).
__global__ __launch_bounds__(256) void k_a1_init(
    const int* __restrict__ edst, int E, unsigned short* __restrict__ pos,
    int* __restrict__ cntg, int PA,
    const float* __restrict__ x1, const float* __restrict__ W,
    const float* __restrict__ b, float* __restrict__ xo, int N, int NBK)
{
    if ((int)blockIdx.x < PA) {
        __shared__ int h[MAXB];
        for (int j = threadIdx.x; j < NBK; j += 256) h[j] = 0;
        __syncthreads();
        int base = blockIdx.x * CHK;
        for (int k = 0; k < CHK / 256; ++k) {
            int i = base + k * 256 + threadIdx.x;
            if (i < E) {
                int bkt = edst[i] >> 7;
                int p = atomicAdd(&h[bkt], 1);
                pos[i] = (unsigned short)p;
            }
        }
        __syncthreads();
        for (int j = threadIdx.x; j < NBK; j += 256)
            cntg[(size_t)j * PA + blockIdx.x] = h[j];
    } else {
        int n = ((int)blockIdx.x - PA) * 256 + (int)threadIdx.x;
        if (n >= N) return;
        float acc[10];
#pragma unroll
        for (int g = 0; g < 10; ++g) acc[g] = b[g];
#pragma unroll
        for (int k = 0; k < 15; ++k) {
            float fv = x1[n * 15 + k];
#pragma unroll
            for (int g = 0; g < 10; ++g) acc[g] += fv * W[k * 10 + g];
        }
        float4* po = (float4*)(xo + n * PAD);
        po[0] = make_float4(fmaxf(acc[0], 0.f), fmaxf(acc[1], 0.f),
                            fmaxf(acc[2], 0.f), fmaxf(acc[3], 0.f));
        po[1] = make_float4(fmaxf(acc[4], 0.f), fmaxf(acc[5], 0.f),
                            fmaxf(acc[6], 0.f), fmaxf(acc[7], 0.f));
        po[2] = make_float4(fmaxf(acc[8], 0.f), fmaxf(acc[9], 0.f), 0.f, 0.f);
    }
}

// Scan stage A: per-1024-block exclusive scan of cntg -> bases, block sums.
__global__ __launch_bounds__(1024) void k_scanA(
    const int* __restrict__ cntg, int* __restrict__ bases,
    int* __restrict__ bsumA, int TOT)
{
    __shared__ int wsum[16];
    int t = threadIdx.x;
    int i = blockIdx.x * 1024 + t;
    int lane = t & 63, w = t >> 6;
    int x = (i < TOT) ? cntg[i] : 0;
    int incl = x;
#pragma unroll
    for (int off = 1; off < 64; off <<= 1) {
        int u = __shfl_up(incl, off);
        if (lane >= off) incl += u;
    }
    if (lane == 63) wsum[w] = incl;
    __syncthreads();
    int woff = 0;
    for (int k = 0; k < w; ++k) woff += wsum[k];
    incl += woff;
    if (i < TOT) bases[i] = incl - x;
    if (t == 1023) bsumA[blockIdx.x] = incl;
}

// Scan stage B: single block scans bsumA (NBLKA <= 512); also zero vsums and
// set rowptr[N] = Etot.
__global__ __launch_bounds__(512) void k_scanB(
    const int* __restrict__ bsumA, int* __restrict__ boffA, int NBLKA,
    float* __restrict__ vsums, int* __restrict__ rowptr, int N, int Etot)
{
    __shared__ int wsum[8];
    int t = threadIdx.x;
    int lane = t & 63, w = t >> 6;
    int x = (t < NBLKA) ? bsumA[t] : 0;
    int incl = x;
#pragma unroll
    for (int off = 1; off < 64; off <<= 1) {
        int u = __shfl_up(incl, off);
        if (lane >= off) incl += u;
    }
    if (lane == 63) wsum[w] = incl;
    __syncthreads();
    int woff = 0;
    for (int k = 0; k < w; ++k) woff += wsum[k];
    incl += woff;
    if (t < NBLKA) boffA[t] = incl - x;
    if (t < 16) vsums[t] = 0.f;
    if (t == 0) rowptr[N] = Etot;
}

// Scan stage C: add block offsets back.
__global__ __launch_bounds__(1024) void k_scanC(
    int* __restrict__ bases, const int* __restrict__ boffA, int TOT)
{
    int i = blockIdx.x * 1024 + threadIdx.x;
    if (i < TOT) bases[i] += boffA[blockIdx.x];
}

// A2: one fully parallel placement pass. No LDS, no atomics.
__global__ __launch_bounds__(256) void k_a2(
    const int* __restrict__ esrc, const int* __restrict__ edst, int E,
    const int* __restrict__ bases, const unsigned short* __restrict__ pos,
    unsigned* __restrict__ pairs, int PA)
{
    int i = blockIdx.x * 256 + threadIdx.x;
    if (i >= E) return;
    int d = edst[i], s = esrc[i];
    int bkt = d >> 7;
    int blk = i / CHK;
    int dest = bases[(size_t)bkt * PA + blk] + (int)pos[i];
    pairs[dest] = (unsigned)s | ((unsigned)(d & 127) << 17);
}

// Fused: blocks [0,NBK) -> per-bucket CSR build; [NBK,..) -> transform layer1.
__global__ __launch_bounds__(256) void k_b_tr1(
    const unsigned* __restrict__ pairs, const int* __restrict__ bases,
    int* __restrict__ rowptr, int* __restrict__ deg, int* __restrict__ sidx,
    int N, int NBK, int PA, int E,
    const float* __restrict__ s0a, const float* __restrict__ x1,
    const float* __restrict__ Wl, const float* __restrict__ Wr,
    unsigned* __restrict__ XLb, float* __restrict__ XR, int NB)
{
    if ((int)blockIdx.x < NBK) {
        __shared__ int cnt[128];
        __shared__ int cur[128];
        __shared__ int wtot;
        int t = threadIdx.x;
        if (t < 128) cnt[t] = 0;
        __syncthreads();
        int b = blockIdx.x;
        int p0 = bases[(size_t)b * PA];
        int p1 = (b + 1 < NBK) ? bases[(size_t)(b + 1) * PA] : E;
        int n0 = b << 7;
        int nn = N - n0; nn = nn < 0 ? 0 : (nn > 128 ? 128 : nn);
        for (int i = p0 + t; i < p1; i += 256) atomicAdd(&cnt[pairs[i] >> 17], 1);
        __syncthreads();
        int x = 0, incl = 0;
        if (t < 128) {
            x = cnt[t] + (t < nn ? 1 : 0);
            incl = x;
            int lane = t & 63;
#pragma unroll
            for (int off = 1; off < 64; off <<= 1) {
                int u = __shfl_up(incl, off);
                if (lane >= off) incl += u;
            }
            if (t == 63) wtot = incl;
        }
        __syncthreads();
        int sb = p0 + (b << 7);  // edge slots before + node slots before
        if (t < 128) {
            if (t >= 64) incl += wtot;
            int st = incl - x;  // exclusive
            if (t < nn) {
                int r = sb + st;
                rowptr[n0 + t] = r;
                deg[n0 + t] = cnt[t] + 1;
                sidx[r] = n0 + t;        // self-loop slot 0
                cur[t] = st + 1;
            } else {
                cur[t] = st;
            }
        }
        __syncthreads();
        for (int i = p0 + t; i < p1; i += 256) {
            unsigned w = pairs[i];
            int l = w >> 17, s = w & 0x1FFFF;
            int off = atomicAdd(&cur[l], 1);
            sidx[sb + off] = s;
        }
    } else {
        int n = ((int)blockIdx.x - NBK) * 256 + (int)threadIdx.x;
        if (n >= N) return;
        transform_body<1>(n, s0a, nullptr, nullptr, x1, Wl, Wr, XLb, XR);
    }
}

// Transform (layers 2/3), streaming-k, no LDS.
template <int NS>
__global__ __launch_bounds__(256) void k_transform(
    const float* __restrict__ s0, const float* __restrict__ s1,
    const float* __restrict__ s2, const float* __restrict__ x1,
    const float* __restrict__ Wl, const float* __restrict__ Wr,
    unsigned* __restrict__ XLb, float* __restrict__ XR, int N)
{
    int n = blockIdx.x * blockDim.x + threadIdx.x;
    if (n >= N) return;
    transform_body<NS>(n, s0, s1, s2, x1, Wl, Wr, XLb, XR);
}

// CSR gather + edge softmax + finalize. 16 lanes/node, batch-2 ILP.
__global__ __launch_bounds__(256) void k_gather(
    const int* __restrict__ rowptr, const int* __restrict__ deg,
    const int* __restrict__ sidx,
    const unsigned* __restrict__ XLb, const float* __restrict__ XR,
    const float* __restrict__ att, const float* __restrict__ b,
    float* __restrict__ xo, int N)
{
    int node = blockIdx.x * 16 + (threadIdx.x >> 4);
    int l16 = threadIdx.x & 15;
    float acc[10];
#pragma unroll
    for (int g = 0; g < 10; ++g) acc[g] = 0.f;
    float den = 0.f;
    float satt[10];
#pragma unroll
    for (int g = 0; g < 10; ++g) satt[g] = att[g];
    if (node < N) {
        const float4* pr = (const float4*)(XR + node * PAD);
        float4 r0 = pr[0], r1 = pr[1], r2 = pr[2];
        float xr[10] = {r0.x, r0.y, r0.z, r0.w, r1.x, r1.y, r1.z, r1.w, r2.x, r2.y};
        int start = rowptr[node];
        int dgr = deg[node];
        int j = l16;
        while (j + 16 < dgr) {
            int s0 = sidx[start + j];
            int s1 = sidx[start + j + 16];
            const unsigned* pl0 = XLb + (size_t)s0 * LP;
            const unsigned* pl1 = XLb + (size_t)s1 * LP;
            uint4 qa = *(const uint4*)pl0;
            unsigned qa4 = pl0[4];
            uint4 qb = *(const uint4*)pl1;
            unsigned qb4 = pl1[4];
            float xa[10] = {bf_lo(qa.x), bf_hi(qa.x), bf_lo(qa.y), bf_hi(qa.y),
                            bf_lo(qa.z), bf_hi(qa.z), bf_lo(qa.w), bf_hi(qa.w),
                            bf_lo(qa4), bf_hi(qa4)};
            float xb[10] = {bf_lo(qb.x), bf_hi(qb.x), bf_lo(qb.y), bf_hi(qb.y),
                            bf_lo(qb.z), bf_hi(qb.z), bf_lo(qb.w), bf_hi(qb.w),
                            bf_lo(qb4), bf_hi(qb4)};
            float ea = 0.f, eb = 0.f;
#pragma unroll
            for (int g = 0; g < 10; ++g) {
                ea += lrelu02(xa[g] + xr[g]) * satt[g];
                eb += lrelu02(xb[g] + xr[g]) * satt[g];
            }
            float exa = __expf(ea), exb = __expf(eb);
#pragma unroll
            for (int g = 0; g < 10; ++g) acc[g] += exa * xa[g] + exb * xb[g];
            den += exa + exb;
            j += 32;
        }
        if (j < dgr) {
            int s = sidx[start + j];
            const unsigned* pl = XLb + (size_t)s * LP;
            uint4 q = *(const uint4*)pl;
            unsigned q4 = pl[4];
            float xl[10] = {bf_lo(q.x), bf_hi(q.x), bf_lo(q.y), bf_hi(q.y),
                            bf_lo(q.z), bf_hi(q.z), bf_lo(q.w), bf_hi(q.w),
                            bf_lo(q4), bf_hi(q4)};
            float e = 0.f;
#pragma unroll
            for (int g = 0; g < 10; ++g) e += lrelu02(xl[g] + xr[g]) * satt[g];
            float ex = __expf(e);
#pragma unroll
            for (int g = 0; g < 10; ++g) acc[g] += ex * xl[g];
            den += ex;
        }
    }
#pragma unroll
    for (int off = 1; off < 16; off <<= 1) {
        den += __shfl_xor(den, off);
#pragma unroll
        for (int g = 0; g < 10; ++g) acc[g] += __shfl_xor(acc[g], off);
    }
    if (node < N && l16 == 0) {
        float inv = 1.f / den;
        float r[10];
#pragma unroll
        for (int g = 0; g < 10; ++g) r[g] = fmaxf(acc[g] * inv + b[g], 0.f);
        float4* po = (float4*)(xo + node * PAD);
        po[0] = make_float4(r[0], r[1], r[2], r[3]);
        po[1] = make_float4(r[4], r[5], r[6], r[7]);
        po[2] = make_float4(r[8], r[9], 0.f, 0.f);
    }
}

// Fused: blocks [0,NB) -> value-head accumulation; [NB,..) -> policy head.
__global__ __launch_bounds__(256) void k_value_policy(
    const float* __restrict__ xc, const float* __restrict__ x1,
    const float* __restrict__ x2,
    const float* __restrict__ vtW, const float* __restrict__ vtb,
    const float* __restrict__ vaW, const float* __restrict__ vab,
    const float* __restrict__ vvW, const float* __restrict__ vvb,
    float* __restrict__ vsums,
    const int* __restrict__ asrc, const int* __restrict__ adst,
    const float* __restrict__ aarm,
    const int* __restrict__ dtgt, const float* __restrict__ darm,
    const float* __restrict__ atW, const float* __restrict__ atb,
    const float* __restrict__ dtW, const float* __restrict__ dtb,
    const float* __restrict__ oaW, const float* __restrict__ oab,
    const float* __restrict__ ovW, const float* __restrict__ ovb,
    float* __restrict__ pm, int NB, int N, int M)
{
    if ((int)blockIdx.x < NB) {
        __shared__ float sred[4][11];
        int t = threadIdx.x;
        int n = blockIdx.x * blockDim.x + t;
        float w = 0.f;
        float wv[10];
#pragma unroll
        for (int c = 0; c < 10; ++c) wv[c] = 0.f;
        if (n < N) {
            float v[20];
#pragma unroll
            for (int j = 0; j < 20; ++j) v[j] = vtb[j];
            {
                const float4* pc = (const float4*)(xc + n * PAD);
                float4 c0 = pc[0], c1 = pc[1], c2 = pc[2];
                float fv[10] = {c0.x, c0.y, c0.z, c0.w, c1.x, c1.y, c1.z, c1.w,
                                c2.x, c2.y};
#pragma unroll
                for (int k = 0; k < 10; ++k)
#pragma unroll
                    for (int j = 0; j < 20; ++j) v[j] += fv[k] * vtW[k * 20 + j];
            }
#pragma unroll
            for (int k = 0; k < 15; ++k) {
                float fv = x1[n * 15 + k];
#pragma unroll
                for (int j = 0; j < 20; ++j) v[j] += fv * vtW[(10 + k) * 20 + j];
            }
#pragma unroll
            for (int k = 0; k < 4; ++k) {
                float fv = x2[k];
#pragma unroll
                for (int j = 0; j < 20; ++j) v[j] += fv * vtW[(25 + k) * 20 + j];
            }
            float sc = vab[0];
#pragma unroll
            for (int j = 0; j < 20; ++j) {
                v[j] = fmaxf(v[j], 0.f);
                sc += v[j] * vaW[j];
            }
            w = __expf(sc);
#pragma unroll
            for (int c = 0; c < 10; ++c) {
                float t2 = vvb[c];
#pragma unroll
                for (int j = 0; j < 20; ++j) t2 += v[j] * vvW[j * 10 + c];
                wv[c] = w * t2;
            }
        }
#pragma unroll
        for (int off = 32; off > 0; off >>= 1) {
            w += __shfl_xor(w, off);
#pragma unroll
            for (int c = 0; c < 10; ++c) wv[c] += __shfl_xor(wv[c], off);
        }
        int wave = t >> 6, lane = t & 63;
        if (lane == 0) {
            sred[wave][0] = w;
#pragma unroll
            for (int c = 0; c < 10; ++c) sred[wave][1 + c] = wv[c];
        }
        __syncthreads();
        if (t == 0) {
#pragma unroll
            for (int c = 0; c < 11; ++c) {
                float s = sred[0][c] + sred[1][c] + sred[2][c] + sred[3][c];
                atomicAdd(&vsums[c], s);
            }
        }
    } else {
        int wave = threadIdx.x >> 6, lane = threadIdx.x & 63;
        int m = ((int)blockIdx.x - NB) * 4 + wave;
        float asc = -1e30f, vsc = 0.f;
        if (m < M) {
            float ord[20];
            bool have = false;
            if (lane < 32) {
                int a = lane;
                int s = asrc[m * 32 + a], d = adst[m * 32 + a];
                float arm = aarm[m * 32 + a];
#pragma unroll
                for (int j = 0; j < 20; ++j) ord[j] = atb[j];
                {
                    const float4* pc = (const float4*)(xc + s * PAD);
                    float4 c0 = pc[0], c1 = pc[1], c2 = pc[2];
                    float fv[10] = {c0.x, c0.y, c0.z, c0.w, c1.x, c1.y, c1.z,
                                    c1.w, c2.x, c2.y};
#pragma unroll
                    for (int k = 0; k < 10; ++k)
#pragma unroll
                        for (int j = 0; j < 20; ++j)
                            ord[j] += fv[k] * atW[k * 20 + j];
                }
                {
                    const float4* pc = (const float4*)(xc + d * PAD);
                    float4 c0 = pc[0], c1 = pc[1], c2 = pc[2];
                    float fv[10] = {c0.x, c0.y, c0.z, c0.w, c1.x, c1.y, c1.z,
                                    c1.w, c2.x, c2.y};
#pragma unroll
                    for (int k = 0; k < 10; ++k)
#pragma unroll
                        for (int j = 0; j < 20; ++j)
                            ord[j] += fv[k] * atW[(10 + k) * 20 + j];
                }
#pragma unroll
                for (int k = 0; k < 12; ++k) {
                    float fv = x1[s * 15 + 3 + k];
#pragma unroll
                    for (int j = 0; j < 20; ++j)
                        ord[j] += fv * atW[(20 + k) * 20 + j];
                }
                float d3 = 0.f, d4 = 0.f;
#pragma unroll
                for (int k = 0; k < 14; ++k) {
                    float fv = x1[d * 15 + 1 + k];
                    if (k == 2) d3 = fv;
                    if (k == 3) d4 = fv;
#pragma unroll
                    for (int j = 0; j < 20; ++j)
                        ord[j] += fv * atW[(32 + k) * 20 + j];
                }
                float extra = 0.6f * arm - 0.7f * (d3 + d4);
#pragma unroll
                for (int j = 0; j < 20; ++j)
                    ord[j] += arm * atW[46 * 20 + j] + extra * atW[47 * 20 + j];
                have = true;
            } else if (lane < 48) {
                int dd = lane - 32;
                int tg = dtgt[m * 16 + dd];
                float arm = darm[m * 16 + dd];
#pragma unroll
                for (int j = 0; j < 20; ++j) ord[j] = dtb[j];
                {
                    const float4* pc = (const float4*)(xc + tg * PAD);
                    float4 c0 = pc[0], c1 = pc[1], c2 = pc[2];
                    float fv[10] = {c0.x, c0.y, c0.z, c0.w, c1.x, c1.y, c1.z,
                                    c1.w, c2.x, c2.y};
#pragma unroll
                    for (int k = 0; k < 10; ++k)
#pragma unroll
                        for (int j = 0; j < 20; ++j)
                            ord[j] += fv[k] * dtW[k * 20 + j];
                }
#pragma unroll
                for (int k = 0; k < 12; ++k) {
                    float fv = x1[tg * 15 + 3 + k];
#pragma unroll
                    for (int j = 0; j < 20; ++j)
                        ord[j] += fv * dtW[(10 + k) * 20 + j];
                }
#pragma unroll
                for (int j = 0; j < 20; ++j) ord[j] += arm * dtW[22 * 20 + j];
                have = true;
            }
            if (have) {
                asc = oab[0]; vsc = ovb[0];
#pragma unroll
                for (int j = 0; j < 20; ++j) {
                    float oj = fmaxf(ord[j], 0.f);
                    asc += oj * oaW[j];
                    vsc += oj * ovW[j];
                }
            }
        }
        float mx = asc;
#pragma unroll
        for (int off = 32; off > 0; off >>= 1) mx = fmaxf(mx, __shfl_xor(mx, off));
        float p = (asc > -1e29f) ? __expf(asc - mx) : 0.f;
        float num = p * vsc;
        float Z = p;
#pragma unroll
        for (int off = 32; off > 0; off >>= 1) {
            Z += __shfl_xor(Z, off);
            num += __shfl_xor(num, off);
        }
        if (m < M && lane == 0) pm[m] = num / Z;
    }
}

// out[1..M] = log_softmax(pm); thread 1023 computes V -> out[0].
__global__ __launch_bounds__(1024) void k_final(
    const float* __restrict__ pm, const float* __restrict__ vsums,
    const float* __restrict__ vlW, const float* __restrict__ vlb,
    float* __restrict__ out, int M)
{
    __shared__ float red[16];
    __shared__ float sval;
    int t = threadIdx.x;
    int wave = t >> 6, lane = t & 63;
    if (t == 1023) {
        float inv = 1.f / vsums[0];
        float V = vlb[0];
#pragma unroll
        for (int j = 0; j < 10; ++j) V += fmaxf(vsums[1 + j] * inv, 0.f) * vlW[j];
        out[0] = tanhf(V);
    }
    float mx = -1e30f;
    for (int i = t; i < M; i += 1024) mx = fmaxf(mx, pm[i]);
#pragma unroll
    for (int off = 32; off > 0; off >>= 1) mx = fmaxf(mx, __shfl_xor(mx, off));
    if (lane == 0) red[wave] = mx;
    __syncthreads();
    if (t == 0) {
        float m2 = red[0];
        for (int i = 1; i < 16; ++i) m2 = fmaxf(m2, red[i]);
        sval = m2;
    }
    __syncthreads();
    float smax = sval;
    float sum = 0.f;
    for (int i = t; i < M; i += 1024) sum += __expf(pm[i] - smax);
#pragma unroll
    for (int off = 32; off > 0; off >>= 1) sum += __shfl_xor(sum, off);
    if (lane == 0) red[wave] = sum;
    __syncthreads();
    if (t == 0) {
        float s2 = 0.f;
        for (int i = 0; i < 16; ++i) s2 += red[i];
        sval = s2;
    }
    __syncthreads();
    float lse = smax + logf(sval);
    for (int i = t; i < M; i += 1024) out[1 + i] = pm[i] - lse;
}

extern "C" void kernel_launch(void* const* d_in, const int* in_sizes, int n_in,
                              void* d_out, int out_size, void* d_ws, size_t ws_size,
                              hipStream_t stream)
{
    const float* x1   = (const float*)d_in[0];
    const float* x2   = (const float*)d_in[1];
    const int*   edges = (const int*)d_in[2];
    const int*   asrc = (const int*)d_in[3];
    const int*   adst = (const int*)d_in[4];
    const float* aarm = (const float*)d_in[5];
    const int*   dtgt = (const int*)d_in[6];
    const float* darm = (const float*)d_in[7];
    const float* initW = (const float*)d_in[8];
    const float* initb = (const float*)d_in[9];
    const float* g1Wl = (const float*)d_in[10];
    const float* g1Wr = (const float*)d_in[11];
    const float* g1att = (const float*)d_in[12];
    const float* g1b = (const float*)d_in[13];
    const float* g2Wl = (const float*)d_in[14];
    const float* g2Wr = (const float*)d_in[15];
    const float* g2att = (const float*)d_in[16];
    const float* g2b = (const float*)d_in[17];
    const float* g3Wl = (const float*)d_in[18];
    const float* g3Wr = (const float*)d_in[19];
    const float* g3att = (const float*)d_in[20];
    const float* g3b = (const float*)d_in[21];
    const float* vtW = (const float*)d_in[22];
    const float* vtb = (const float*)d_in[23];
    const float* vaW = (const float*)d_in[24];
    const float* vab = (const float*)d_in[25];
    const float* vvW = (const float*)d_in[26];
    const float* vvb = (const float*)d_in[27];
    const float* vlW = (const float*)d_in[28];
    const float* vlb = (const float*)d_in[29];
    const float* atW = (const float*)d_in[30];
    const float* atb = (const float*)d_in[31];
    const float* dtW = (const float*)d_in[32];
    const float* dtb = (const float*)d_in[33];
    const float* oaW = (const float*)d_in[34];
    const float* oab = (const float*)d_in[35];
    const float* ovW = (const float*)d_in[36];
    const float* ovb = (const float*)d_in[37];

    const int N = in_sizes[0] / 15;
    const int E = in_sizes[2] / 2;
    const int M = in_sizes[3] / 32;
    const int Etot = E + N;
    const int NBK = (N + 127) >> 7;
    const int PA = (E + CHK - 1) / CHK;
    const int TOT = NBK * PA;

    float* ws = (float*)d_ws;
    size_t off = 0;
    float* XU = ws + off; off += (size_t)N * PAD;
    float* XA = ws + off; off += (size_t)N * PAD;
    float* XB = ws + off; off += (size_t)N * PAD;
    float* XC = ws + off; off += (size_t)N * PAD;
    unsigned* XLb = (unsigned*)(ws + off); off += (size_t)N * LP;
    float* XR = ws + off; off += (size_t)N * PAD;
    int* sidx = (int*)(ws + off); off += Etot;
    unsigned* pairs = (unsigned*)(ws + off); off += E;
    int* deg = (int*)(ws + off); off += N;
    int* rowptr = (int*)(ws + off); off += N + 8;
    int* cntg = (int*)(ws + off); off += TOT + 8;
    int* bases = (int*)(ws + off); off += TOT + 8;
    int* bsumA = (int*)(ws + off); off += 512;
    int* boffA = (int*)(ws + off); off += 512;
    float* VS = ws + off; off += 16;
    float* PM = ws + off; off += M;
    // pos (u16, E entries = 6.4MB) overlays XA..XB (9.6MB); dead before gather1.
    unsigned short* pos = (unsigned short*)XA;

    float* outp = (float*)d_out;

    const int NB = (N + 255) / 256;
    const int NG = (N + 15) / 16;
    const int PB = (M + 3) / 4;
    const int SCA = (TOT + 1023) / 1024;  // must be <= 512 for k_scanB
    const int* esrc = edges;
    const int* edst = edges + E;

    k_a1_init<<<PA + NB, 256, 0, stream>>>(edst, E, pos, cntg, PA,
                                           x1, initW, initb, XU, N, NBK);
    k_scanA<<<SCA, 1024, 0, stream>>>(cntg, bases, bsumA, TOT);
    k_scanB<<<1, 512, 0, stream>>>(bsumA, boffA, SCA, VS, rowptr, N, Etot);
    k_scanC<<<SCA, 1024, 0, stream>>>(bases, boffA, TOT);
    k_a2<<<(E + 255) / 256, 256, 0, stream>>>(esrc, edst, E, bases, pos, pairs, PA);
    k_b_tr1<<<NBK + NB, 256, 0, stream>>>(pairs, bases, rowptr, deg, sidx, N, NBK, PA, E,
                                          XU, x1, g1Wl, g1Wr, XLb, XR, NB);
    k_gather<<<NG, 256, 0, stream>>>(rowptr, deg, sidx, XLb, XR, g1att, g1b, XA, N);

    k_transform<2><<<NB, 256, 0, stream>>>(XA, XU, nullptr, x1, g2Wl, g2Wr, XLb, XR, N);
    k_gather<<<NG, 256, 0, stream>>>(rowptr, deg, sidx, XLb, XR, g2att, g2b, XB, N);

    k_transform<3><<<NB, 256, 0, stream>>>(XB, XA, XU, x1, g3Wl, g3Wr, XLb, XR, N);
    k_gather<<<NG, 256, 0, stream>>>(rowptr, deg, sidx, XLb, XR, g3att, g3b, XC, N);

    k_value_policy<<<NB + PB, 256, 0, stream>>>(XC, x1, x2, vtW, vtb, vaW, vab,
                                                vvW, vvb, VS, asrc, adst, aarm,
                                                dtgt, darm, atW, atb, dtW, dtb,
                                                oaW, oab, ovW, ovb, PM, NB, N, M);
    k_final<<<1, 1024, 0, stream>>>(PM, VS, vlW, vlb, outp, M);
}